// Round 19
// baseline (1213.155 us; speedup 1.0000x reference)
//
#include <hip/hip_runtime.h>
#include <math.h>

#define HW 4096
#define KTOT 2304   // 256 * 9

typedef __attribute__((ext_vector_type(8))) short short8v;
typedef __attribute__((ext_vector_type(4))) float float4v;

__device__ __forceinline__ unsigned int bf16rne(float f) {
  unsigned int x = __float_as_uint(f);
  return (x + 0x7fffu + ((x >> 16) & 1u)) >> 16;
}

__device__ __forceinline__ unsigned int cvtpk(float lo, float hi) {
  unsigned int r;
  asm("v_cvt_pk_bf16_f32 %0, %1, %2" : "=v"(r) : "v"(lo), "v"(hi));
  return r;
}

__device__ __forceinline__ unsigned int bilin_pack(unsigned int u0, unsigned int u1,
                                                   unsigned int u2, unsigned int u3,
                                                   float w0, float w1, float w2, float w3) {
  float lo = w0 * __uint_as_float(u0 << 16) + w1 * __uint_as_float(u1 << 16) +
             w2 * __uint_as_float(u2 << 16) + w3 * __uint_as_float(u3 << 16);
  float hi = w0 * __uint_as_float(u0 & 0xFFFF0000u) + w1 * __uint_as_float(u1 & 0xFFFF0000u) +
             w2 * __uint_as_float(u2 & 0xFFFF0000u) + w3 * __uint_as_float(u3 & 0xFFFF0000u);
  return cvtpk(lo, hi);
}

#define AG_STORE(p, v) __hip_atomic_store((p), (v), __ATOMIC_RELEASE, __HIP_MEMORY_SCOPE_AGENT)
#define AG_LOAD(p)     __hip_atomic_load((p), __ATOMIC_ACQUIRE, __HIP_MEMORY_SCOPE_AGENT)

// Grid barrier under guaranteed co-residency (grid=512 <= 2 blk/CU x 256 CU;
// all blocks dispatch into free slots immediately -> no deadlock).
__device__ __forceinline__ void grid_bar(unsigned* cnt) {
  __syncthreads();
  if (threadIdx.x == 0) {
    __hip_atomic_fetch_add(cnt, 1u, __ATOMIC_ACQ_REL, __HIP_MEMORY_SCOPE_AGENT);
    while (__hip_atomic_load(cnt, __ATOMIC_ACQUIRE, __HIP_MEMORY_SCOPE_AGENT) < 512u)
      __builtin_amdgcn_s_sleep(2);
  }
  __syncthreads();
}

// ------------------------------------------------------------------
// ws layout (float offsets):
//   589824   : xT       [8][4096][256] bf16
//   4784128  : wB       [72][16][64][8] bf16
//   5079040  : wOffB    [72][2][64][8] bf16
//   5115904  : partS    [256 oc][512] f32
//   5246976  : partQ    [256 oc][512] f32
//   5378048  : statsM   [256] f32
//   5378304  : statsR   [256] f32
//   5378560  : barrier counters (2 x u32)  -- memset to 0 each call
// ------------------------------------------------------------------

// Merged: blocks [0,512) transpose x -> NHWC bf16 via LDS (coalesced both
// sides; n = bid&7 XCD-aligned); [512,800) pack w_conv; [800,836) w_offset.
__global__ __launch_bounds__(256) void k_tx_prep(const float* __restrict__ x,
                                                 const float* __restrict__ wc,
                                                 const float* __restrict__ wo,
                                                 ushort* __restrict__ xT,
                                                 ushort* __restrict__ wB,
                                                 ushort* __restrict__ wOB) {
  __shared__ unsigned s32[64 * 129];   // 33 KB, pad-129 -> conflict-free
  int bid = blockIdx.x;
  if (bid < 512) {
    int n = bid & 7, p0 = (bid >> 3) << 6;
    int t = threadIdx.x;
    int pixr = t & 63;
    int cq = t >> 6;
    const float* xb = x + ((size_t)n * 256) * HW + p0 + pixr;
#pragma unroll 4
    for (int g = 0; g < 32; ++g) {
      int c0 = (g << 3) + (cq << 1);
      float v0 = xb[(size_t)c0 * HW];
      float v1 = xb[(size_t)(c0 + 1) * HW];
      s32[pixr * 129 + (c0 >> 1)] = cvtpk(v0, v1);
    }
    __syncthreads();
    int cslot = t & 31;
    int pw = t >> 5;
#pragma unroll
    for (int pass = 0; pass < 8; ++pass) {
      int pix = (pass << 3) + pw;
      uint4 v = *reinterpret_cast<const uint4*>(&s32[pix * 129 + (cslot << 2)]);
      *reinterpret_cast<uint4*>(
          &xT[((size_t)(n * 4096 + p0 + pix)) * 256 + (cslot << 3)]) = v;
    }
  } else if (bid < 800) {
    int t = (bid - 512) * 256 + threadIdx.x;   // 73728
    int ks = t >> 10;
    int l = t & 63;
    int of = (t >> 6) & 15;
    int kk = ks >> 3;
    int cbase = ((ks & 7) << 5) + ((l >> 4) << 3);
    int oc = (of << 4) + (l & 15);
    unsigned int u[8];
#pragma unroll
    for (int j = 0; j < 8; ++j)
      u[j] = bf16rne(wc[(size_t)oc * KTOT + (size_t)(cbase + j) * 9 + kk]);
    *reinterpret_cast<uint4*>(&wB[(size_t)t * 8]) =
        make_uint4(u[0] | (u[1] << 16), u[2] | (u[3] << 16),
                   u[4] | (u[5] << 16), u[6] | (u[7] << 16));
  } else {
    int t = (bid - 800) * 256 + threadIdx.x;   // 9216
    int ks = t >> 7;
    int l = t & 63;
    int of = (t >> 6) & 1;
    int kk = ks >> 3;
    int cbase = ((ks & 7) << 5) + ((l >> 4) << 3);
    int oc = (of << 4) + (l & 15);
    unsigned int u[8];
#pragma unroll
    for (int j = 0; j < 8; ++j)
      u[j] = (oc < 18) ? bf16rne(wo[(size_t)oc * KTOT + (size_t)(cbase + j) * 9 + kk]) : 0u;
    *reinterpret_cast<uint4*>(&wOB[(size_t)t * 8]) =
        make_uint4(u[0] | (u[1] << 16), u[2] | (u[3] << 16),
                   u[4] | (u[5] << 16), u[6] | (u[7] << 16));
  }
}

// ------------------------------------------------------------------
// FULLY FUSED: offset conv + deformable conv + BN stats + BN+SiLU apply.
// Plain launch, grid 512 x 512 thr, hand-rolled grid barrier (co-resident
// by capacity). Cross-block data via agent-scope atomics (XCD L2 fix).
// ------------------------------------------------------------------
__global__ __launch_bounds__(512, 4) void k_dfull(
    const ushort* __restrict__ xT, const ushort* __restrict__ wB,
    const ushort* __restrict__ wOB, const float* __restrict__ b_off,
    const float* __restrict__ gamma, const float* __restrict__ beta,
    float* __restrict__ out, float* __restrict__ partS,
    float* __restrict__ partQ, float* __restrict__ statsM,
    float* __restrict__ statsR, unsigned* __restrict__ bar) {
  __shared__ ushort s_val[2][64 * 64];   // 16 KB
  __shared__ int4   s_gi[9][64];         // 9.2 KB
  __shared__ float4 s_gw[9][64];         // 9.2 KB
  __shared__ float  s_off[64][20];       // 5 KB
  __shared__ float2 s_red[8];

  int bid = blockIdx.x;
  int n = bid & 7, ho = bid >> 3;
  int t = threadIdx.x;
  int lane = t & 63, wave = t >> 6;
  int coct = lane & 7;
  int p = (wave << 3) + (lane >> 3);

  const ushort* xTn = xT + (size_t)n * 4096 * 256;

  // ======== phase 1: offset conv (64 pix x 18 oc) ========
  {
    int ocf = wave & 1, pixf = wave >> 1;
    float4v aoff = (float4v)0.f;

    auto srcp = [&](int kk, const ushort*& s, bool& v) {
      int ky = kk / 3, kx = kk - ky * 3;
      int oy = ho + ky - 1, ox = p + kx - 1;
      v = (oy >= 0) & (oy < 64) & (ox >= 0) & (ox < 64);
      s = xTn + (size_t)(oy * 64 + ox) * 256 + (coct << 3);
    };
    auto ld = [&](uint4& a, const ushort* s, bool v, int cg) {
      a = v ? *reinterpret_cast<const uint4*>(s + (cg << 6)) : make_uint4(0, 0, 0, 0);
    };
    auto ostep = [&](uint4 a, int ksb, int buf) {
      short8v wf[2];
#pragma unroll
      for (int ks2 = 0; ks2 < 2; ++ks2)
        wf[ks2] = *reinterpret_cast<const short8v*>(
            &wOB[(((size_t)((ksb + ks2) * 2 + ocf)) * 64 + lane) * 8]);
      *reinterpret_cast<uint4*>(&s_val[buf][p * 64 + ((coct ^ (p & 7)) << 3)]) = a;
      asm volatile("s_waitcnt lgkmcnt(0)" ::: "memory");
      __builtin_amdgcn_s_barrier();
#pragma unroll
      for (int ks2 = 0; ks2 < 2; ++ks2) {
        int row = (pixf << 4) + (lane & 15);
        int g = (ks2 << 2) + (lane >> 4);
        int slot = g ^ (row & 7);
        short8v vf = *reinterpret_cast<const short8v*>(&s_val[buf][row * 64 + slot * 8]);
        aoff = __builtin_amdgcn_mfma_f32_16x16x32_bf16(wf[ks2], vf, aoff, 0, 0, 0);
      }
    };

    const ushort* cs;
    bool cv;
    srcp(0, cs, cv);
    uint4 A, B;
    ld(A, cs, cv, 0);
    for (int kk = 0; kk < 9; ++kk) {
      int ksb = kk << 3;
      ld(B, cs, cv, 1);
      ostep(A, ksb + 0, 0);
      ld(A, cs, cv, 2);
      ostep(B, ksb + 2, 1);
      ld(B, cs, cv, 3);
      ostep(A, ksb + 4, 0);
      const ushort* ns = cs;
      bool nv = cv;
      if (kk < 8) {
        srcp(kk + 1, ns, nv);
        ld(A, ns, nv, 0);
      }
      ostep(B, ksb + 6, 1);
      cs = ns;
      cv = nv;
    }
    int pixcol = (pixf << 4) + (lane & 15);
#pragma unroll
    for (int j = 0; j < 4; ++j) {
      int oc = (ocf << 4) + ((lane >> 4) << 2) + j;
      if (oc < 18) s_off[pixcol][oc] = aoff[j] + b_off[oc];
    }
  }
  __syncthreads();

  // ======== phase 2: bilinear geometry ========
  for (int e = t; e < 576; e += 512) {
    int pix = e & 63, kk = e >> 6;
    int ky = kk / 3, kx = kk - ky * 3;
    float dy = s_off[pix][2 * kk], dx = s_off[pix][2 * kk + 1];
    float py = (float)(ho - 1 + ky) + dy;
    float px = (float)(pix - 1 + kx) + dx;
    float y0f = floorf(py), x0f = floorf(px);
    float ly = py - y0f, lx = px - x0f;
    int y0 = (int)y0f, x0 = (int)x0f;
    int y1 = y0 + 1, x1 = x0 + 1;
    float vy0 = (y0 >= 0 && y0 < 64) ? 1.f : 0.f;
    float vy1 = (y1 >= 0 && y1 < 64) ? 1.f : 0.f;
    float vx0 = (x0 >= 0 && x0 < 64) ? 1.f : 0.f;
    float vx1 = (x1 >= 0 && x1 < 64) ? 1.f : 0.f;
    int cy0 = min(max(y0, 0), 63) << 6, cy1 = min(max(y1, 0), 63) << 6;
    int cx0 = min(max(x0, 0), 63), cx1 = min(max(x1, 0), 63);
    s_gi[kk][pix] = make_int4((cy0 + cx0) << 8, (cy0 + cx1) << 8,
                              (cy1 + cx0) << 8, (cy1 + cx1) << 8);
    s_gw[kk][pix] = make_float4((1.f - ly) * (1.f - lx) * vy0 * vx0,
                                (1.f - ly) * lx * vy0 * vx1,
                                ly * (1.f - lx) * vy1 * vx0,
                                ly * lx * vy1 * vx1);
  }
  __syncthreads();

  // ======== phase 3: main loop (R13 deform10 verbatim) ========
  float4v acc[2][4];
#pragma unroll
  for (int a = 0; a < 2; ++a)
#pragma unroll
    for (int b = 0; b < 4; ++b) acc[a][b] = (float4v)0.f;

  uint4 TA[4], TB[4];

  auto issue = [&](uint4 (&T)[4], int kk, int cg) {
    int4 g = s_gi[kk][p];
    int cb = (cg << 6) + (coct << 3);
    T[0] = *reinterpret_cast<const uint4*>(xTn + g.x + cb);
    T[1] = *reinterpret_cast<const uint4*>(xTn + g.y + cb);
    T[2] = *reinterpret_cast<const uint4*>(xTn + g.z + cb);
    T[3] = *reinterpret_cast<const uint4*>(xTn + g.w + cb);
  };

  auto step = [&](uint4 (&T)[4], int kk, int ks0, int buf) {
    short8v wf[2][2];
#pragma unroll
    for (int ks2 = 0; ks2 < 2; ++ks2)
#pragma unroll
      for (int mf = 0; mf < 2; ++mf)
        wf[ks2][mf] = *reinterpret_cast<const short8v*>(
            &wB[(((size_t)((ks0 + ks2) * 16 + (wave << 1) + mf)) * 64 + lane) * 8]);
    float4 w = s_gw[kk][p];
    uint4 r;
    r.x = bilin_pack(T[0].x, T[1].x, T[2].x, T[3].x, w.x, w.y, w.z, w.w);
    r.y = bilin_pack(T[0].y, T[1].y, T[2].y, T[3].y, w.x, w.y, w.z, w.w);
    r.z = bilin_pack(T[0].z, T[1].z, T[2].z, T[3].z, w.x, w.y, w.z, w.w);
    r.w = bilin_pack(T[0].w, T[1].w, T[2].w, T[3].w, w.x, w.y, w.z, w.w);
    *reinterpret_cast<uint4*>(&s_val[buf][p * 64 + ((coct ^ (p & 7)) << 3)]) = r;
    asm volatile("s_waitcnt lgkmcnt(0)" ::: "memory");
    __builtin_amdgcn_s_barrier();
    __builtin_amdgcn_s_setprio(1);
#pragma unroll
    for (int ks2 = 0; ks2 < 2; ++ks2) {
#pragma unroll
      for (int pf = 0; pf < 4; ++pf) {
        int row = (pf << 4) + (lane & 15);
        int g = (ks2 << 2) + (lane >> 4);
        int slot = g ^ (row & 7);
        short8v vf = *reinterpret_cast<const short8v*>(&s_val[buf][row * 64 + slot * 8]);
#pragma unroll
        for (int mf = 0; mf < 2; ++mf)
          acc[mf][pf] = __builtin_amdgcn_mfma_f32_16x16x32_bf16(
              wf[ks2][mf], vf, acc[mf][pf], 0, 0, 0);
      }
    }
    __builtin_amdgcn_s_setprio(0);
  };

  issue(TA, 0, 0);
  for (int kk = 0; kk < 9; ++kk) {
    int ks0 = kk << 3;
    issue(TB, kk, 1);
    step(TA, kk, ks0 + 0, 0);
    issue(TA, kk, 2);
    step(TB, kk, ks0 + 2, 1);
    issue(TB, kk, 3);
    step(TA, kk, ks0 + 4, 0);
    if (kk < 8) issue(TA, kk + 1, 0);
    step(TB, kk, ks0 + 6, 1);
  }

  // ======== epilogue A: BN partials (agent-scope stores) ========
  float s[2][4], q[2][4];
#pragma unroll
  for (int mf = 0; mf < 2; ++mf)
#pragma unroll
    for (int j = 0; j < 4; ++j) {
      float ss = 0.f, qq = 0.f;
#pragma unroll
      for (int pf = 0; pf < 4; ++pf) {
        float v = acc[mf][pf][j];
        ss += v;
        qq += v * v;
      }
      s[mf][j] = ss;
      q[mf][j] = qq;
    }
#pragma unroll
  for (int o = 1; o < 16; o <<= 1) {
#pragma unroll
    for (int mf = 0; mf < 2; ++mf)
#pragma unroll
      for (int j = 0; j < 4; ++j) {
        s[mf][j] += __shfl_xor(s[mf][j], o);
        q[mf][j] += __shfl_xor(q[mf][j], o);
      }
  }
  if ((lane & 15) == 0) {
#pragma unroll
    for (int mf = 0; mf < 2; ++mf)
#pragma unroll
      for (int j = 0; j < 4; ++j) {
        int oc = (wave << 5) + (mf << 4) + ((lane >> 4) << 2) + j;
        size_t idx = (size_t)oc * 512 + bid;
        AG_STORE(&partS[idx], s[mf][j]);
        AG_STORE(&partQ[idx], q[mf][j]);
      }
  }

  grid_bar(&bar[0]);

  // ======== epilogue B: stats (blocks 0..255, one oc each) ========
  if (bid < 256) {
    int oc = bid;
    float ss = AG_LOAD(&partS[(size_t)oc * 512 + t]);
    float qq = AG_LOAD(&partQ[(size_t)oc * 512 + t]);
#pragma unroll
    for (int o = 32; o; o >>= 1) {
      ss += __shfl_down(ss, o);
      qq += __shfl_down(qq, o);
    }
    if (lane == 0) s_red[wave] = make_float2(ss, qq);
    __syncthreads();
    if (t == 0) {
      float S = 0.f, Q = 0.f;
#pragma unroll
      for (int i = 0; i < 8; ++i) {
        S += s_red[i].x;
        Q += s_red[i].y;
      }
      float mean = S / 32768.f;
      float var = Q / 32768.f - mean * mean;
      AG_STORE(&statsM[oc], mean);
      AG_STORE(&statsR[oc], rsqrtf(var + 1e-5f));
    }
  }

  grid_bar(&bar[1]);

  // ======== epilogue C: BN+SiLU on in-register acc, final write ========
#pragma unroll
  for (int mf = 0; mf < 2; ++mf) {
    int ocb = (wave << 5) + (mf << 4) + ((lane >> 4) << 2);
#pragma unroll
    for (int j = 0; j < 4; ++j) {
      int oc = ocb + j;
      float m = AG_LOAD(&statsM[oc]);
      float r = AG_LOAD(&statsR[oc]);
      float g = gamma[oc] * r;
      float bb = beta[oc] - m * g;
      float* op = out + (((size_t)(n * 256 + oc)) * 64 + ho) * 64;
#pragma unroll
      for (int pf = 0; pf < 4; ++pf) {
        int wo = (pf << 4) + (lane & 15);
        float y = acc[mf][pf][j] * g + bb;
        op[wo] = y / (1.f + expf(-y));
      }
    }
  }
}

extern "C" void kernel_launch(void* const* d_in, const int* in_sizes, int n_in,
                              void* d_out, int out_size, void* d_ws, size_t ws_size,
                              hipStream_t stream) {
  const float* x      = (const float*)d_in[0];
  const float* w_off  = (const float*)d_in[1];
  const float* b_off  = (const float*)d_in[2];
  const float* w_conv = (const float*)d_in[3];
  const float* gamma  = (const float*)d_in[4];
  const float* beta   = (const float*)d_in[5];
  float* out = (float*)d_out;

  float* ws       = (float*)d_ws;
  ushort* ws_xT   = (ushort*)(ws + 589824);           // [8][4096][256] bf16
  ushort* ws_wB   = (ushort*)(ws + 4784128);          // deform weight frags
  ushort* ws_wOB  = (ushort*)(ws + 5079040);          // offset weight frags
  float*  ws_pS   = ws + 5115904;                     // [256][512] f32
  float*  ws_pQ   = ws + 5246976;                     // [256][512] f32
  float*  ws_sM   = ws + 5378048;                     // [256] f32
  float*  ws_sR   = ws + 5378304;                     // [256] f32
  unsigned* ws_bar = (unsigned*)(ws + 5378560);       // 2 x u32 barrier ctrs

  hipMemsetAsync(ws_bar, 0, 2 * sizeof(unsigned), stream);
  k_tx_prep<<<836, 256, 0, stream>>>(x, w_conv, w_off, ws_xT, ws_wB, ws_wOB);
  k_dfull<<<512, 512, 0, stream>>>(ws_xT, ws_wB, ws_wOB, b_off, gamma, beta,
                                   out, ws_pS, ws_pQ, ws_sM, ws_sR, ws_bar);
}

// Round 21
// 122.373 us; speedup vs baseline: 9.9136x; 9.9136x over previous
//
#include <hip/hip_runtime.h>
#include <math.h>

#define HW 4096
#define KTOT 2304   // 256 * 9

typedef __attribute__((ext_vector_type(8))) short short8v;
typedef __attribute__((ext_vector_type(4))) float float4v;

__device__ __forceinline__ unsigned int bf16rne(float f) {
  unsigned int x = __float_as_uint(f);
  return (x + 0x7fffu + ((x >> 16) & 1u)) >> 16;
}

__device__ __forceinline__ unsigned int cvtpk(float lo, float hi) {
  unsigned int r;
  asm("v_cvt_pk_bf16_f32 %0, %1, %2" : "=v"(r) : "v"(lo), "v"(hi));
  return r;
}

__device__ __forceinline__ unsigned int bilin_pack(unsigned int u0, unsigned int u1,
                                                   unsigned int u2, unsigned int u3,
                                                   float w0, float w1, float w2, float w3) {
  float lo = w0 * __uint_as_float(u0 << 16) + w1 * __uint_as_float(u1 << 16) +
             w2 * __uint_as_float(u2 << 16) + w3 * __uint_as_float(u3 << 16);
  float hi = w0 * __uint_as_float(u0 & 0xFFFF0000u) + w1 * __uint_as_float(u1 & 0xFFFF0000u) +
             w2 * __uint_as_float(u2 & 0xFFFF0000u) + w3 * __uint_as_float(u3 & 0xFFFF0000u);
  return cvtpk(lo, hi);
}

#define RX_STORE(p, v) __hip_atomic_store((p), (v), __ATOMIC_RELAXED, __HIP_MEMORY_SCOPE_AGENT)
#define RX_LOAD(p)     __hip_atomic_load((p), __ATOMIC_RELAXED, __HIP_MEMORY_SCOPE_AGENT)

// Low-contention grid barrier (grid=512 co-resident by capacity).
// Arrivals: relaxed fetch_add on counter line (memory-side atomics).
// Spin: RELAXED polls on a SEPARATE flag line (no per-poll cache maint).
// One release fence before arrival, one acquire fence after release seen.
__device__ __forceinline__ void grid_bar(unsigned* cnt, unsigned* flag,
                                         unsigned gen) {
  __syncthreads();
  if (threadIdx.x == 0) {
    __builtin_amdgcn_fence(__ATOMIC_RELEASE, "agent");
    unsigned a = __hip_atomic_fetch_add(cnt, 1u, __ATOMIC_RELAXED,
                                        __HIP_MEMORY_SCOPE_AGENT);
    if (a == 511u) {
      __hip_atomic_store(flag, gen, __ATOMIC_RELAXED, __HIP_MEMORY_SCOPE_AGENT);
    } else {
      while (__hip_atomic_load(flag, __ATOMIC_RELAXED,
                               __HIP_MEMORY_SCOPE_AGENT) < gen)
        __builtin_amdgcn_s_sleep(8);
    }
    __builtin_amdgcn_fence(__ATOMIC_ACQUIRE, "agent");
  }
  __syncthreads();
}

// ------------------------------------------------------------------
// ws layout (float offsets):
//   589824   : xT       [8][4096][256] bf16
//   4784128  : wB       [72][16][64][8] bf16
//   5079040  : wOffB    [72][2][64][8] bf16
//   5115904  : partS    [256 oc][512] f32
//   5246976  : partQ    [256 oc][512] f32
//   5378048  : statsM   [256] f32
//   5378304  : statsR   [256] f32
//   5378560  : barrier area (64 u32: cnt0 @0, cnt1 @16, flag @32)
// ------------------------------------------------------------------

// Merged: blocks [0,512) transpose x -> NHWC bf16 via LDS (coalesced both
// sides; n = bid&7 XCD-aligned); [512,800) pack w_conv; [800,836) w_offset.
__global__ __launch_bounds__(256) void k_tx_prep(const float* __restrict__ x,
                                                 const float* __restrict__ wc,
                                                 const float* __restrict__ wo,
                                                 ushort* __restrict__ xT,
                                                 ushort* __restrict__ wB,
                                                 ushort* __restrict__ wOB) {
  __shared__ unsigned s32[64 * 129];   // 33 KB, pad-129 -> conflict-free
  int bid = blockIdx.x;
  if (bid < 512) {
    int n = bid & 7, p0 = (bid >> 3) << 6;
    int t = threadIdx.x;
    int pixr = t & 63;
    int cq = t >> 6;
    const float* xb = x + ((size_t)n * 256) * HW + p0 + pixr;
#pragma unroll 4
    for (int g = 0; g < 32; ++g) {
      int c0 = (g << 3) + (cq << 1);
      float v0 = xb[(size_t)c0 * HW];
      float v1 = xb[(size_t)(c0 + 1) * HW];
      s32[pixr * 129 + (c0 >> 1)] = cvtpk(v0, v1);
    }
    __syncthreads();
    int cslot = t & 31;
    int pw = t >> 5;
#pragma unroll
    for (int pass = 0; pass < 8; ++pass) {
      int pix = (pass << 3) + pw;
      uint4 v = *reinterpret_cast<const uint4*>(&s32[pix * 129 + (cslot << 2)]);
      *reinterpret_cast<uint4*>(
          &xT[((size_t)(n * 4096 + p0 + pix)) * 256 + (cslot << 3)]) = v;
    }
  } else if (bid < 800) {
    int t = (bid - 512) * 256 + threadIdx.x;   // 73728
    int ks = t >> 10;
    int l = t & 63;
    int of = (t >> 6) & 15;
    int kk = ks >> 3;
    int cbase = ((ks & 7) << 5) + ((l >> 4) << 3);
    int oc = (of << 4) + (l & 15);
    unsigned int u[8];
#pragma unroll
    for (int j = 0; j < 8; ++j)
      u[j] = bf16rne(wc[(size_t)oc * KTOT + (size_t)(cbase + j) * 9 + kk]);
    *reinterpret_cast<uint4*>(&wB[(size_t)t * 8]) =
        make_uint4(u[0] | (u[1] << 16), u[2] | (u[3] << 16),
                   u[4] | (u[5] << 16), u[6] | (u[7] << 16));
  } else {
    int t = (bid - 800) * 256 + threadIdx.x;   // 9216
    int ks = t >> 7;
    int l = t & 63;
    int of = (t >> 6) & 1;
    int kk = ks >> 3;
    int cbase = ((ks & 7) << 5) + ((l >> 4) << 3);
    int oc = (of << 4) + (l & 15);
    unsigned int u[8];
#pragma unroll
    for (int j = 0; j < 8; ++j)
      u[j] = (oc < 18) ? bf16rne(wo[(size_t)oc * KTOT + (size_t)(cbase + j) * 9 + kk]) : 0u;
    *reinterpret_cast<uint4*>(&wOB[(size_t)t * 8]) =
        make_uint4(u[0] | (u[1] << 16), u[2] | (u[3] << 16),
                   u[4] | (u[5] << 16), u[6] | (u[7] << 16));
  }
}

// ------------------------------------------------------------------
// FULLY FUSED: offset conv + deformable conv + BN stats + BN+SiLU apply.
// Plain launch, grid 512 x 512 thr, low-contention grid barrier.
// Cross-block data via relaxed agent atomics (coherence point), ordered
// by the barrier's release/acquire fences.
// ------------------------------------------------------------------
__global__ __launch_bounds__(512, 4) void k_dfull(
    const ushort* __restrict__ xT, const ushort* __restrict__ wB,
    const ushort* __restrict__ wOB, const float* __restrict__ b_off,
    const float* __restrict__ gamma, const float* __restrict__ beta,
    float* __restrict__ out, float* __restrict__ partS,
    float* __restrict__ partQ, float* __restrict__ statsM,
    float* __restrict__ statsR, unsigned* __restrict__ bar) {
  __shared__ ushort s_val[2][64 * 64];   // 16 KB
  __shared__ int4   s_gi[9][64];         // 9.2 KB
  __shared__ float4 s_gw[9][64];         // 9.2 KB
  __shared__ float  s_off[64][20];       // 5 KB (reused as stats stage)
  __shared__ float2 s_red[8];

  int bid = blockIdx.x;
  int n = bid & 7, ho = bid >> 3;
  int t = threadIdx.x;
  int lane = t & 63, wave = t >> 6;
  int coct = lane & 7;
  int p = (wave << 3) + (lane >> 3);

  const ushort* xTn = xT + (size_t)n * 4096 * 256;

  // ======== phase 1: offset conv (64 pix x 18 oc) ========
  {
    int ocf = wave & 1, pixf = wave >> 1;
    float4v aoff = (float4v)0.f;

    auto srcp = [&](int kk, const ushort*& s, bool& v) {
      int ky = kk / 3, kx = kk - ky * 3;
      int oy = ho + ky - 1, ox = p + kx - 1;
      v = (oy >= 0) & (oy < 64) & (ox >= 0) & (ox < 64);
      s = xTn + (size_t)(oy * 64 + ox) * 256 + (coct << 3);
    };
    auto ld = [&](uint4& a, const ushort* s, bool v, int cg) {
      a = v ? *reinterpret_cast<const uint4*>(s + (cg << 6)) : make_uint4(0, 0, 0, 0);
    };
    auto ostep = [&](uint4 a, int ksb, int buf) {
      short8v wf[2];
#pragma unroll
      for (int ks2 = 0; ks2 < 2; ++ks2)
        wf[ks2] = *reinterpret_cast<const short8v*>(
            &wOB[(((size_t)((ksb + ks2) * 2 + ocf)) * 64 + lane) * 8]);
      *reinterpret_cast<uint4*>(&s_val[buf][p * 64 + ((coct ^ (p & 7)) << 3)]) = a;
      asm volatile("s_waitcnt lgkmcnt(0)" ::: "memory");
      __builtin_amdgcn_s_barrier();
#pragma unroll
      for (int ks2 = 0; ks2 < 2; ++ks2) {
        int row = (pixf << 4) + (lane & 15);
        int g = (ks2 << 2) + (lane >> 4);
        int slot = g ^ (row & 7);
        short8v vf = *reinterpret_cast<const short8v*>(&s_val[buf][row * 64 + slot * 8]);
        aoff = __builtin_amdgcn_mfma_f32_16x16x32_bf16(wf[ks2], vf, aoff, 0, 0, 0);
      }
    };

    const ushort* cs;
    bool cv;
    srcp(0, cs, cv);
    uint4 A, B;
    ld(A, cs, cv, 0);
    for (int kk = 0; kk < 9; ++kk) {
      int ksb = kk << 3;
      ld(B, cs, cv, 1);
      ostep(A, ksb + 0, 0);
      ld(A, cs, cv, 2);
      ostep(B, ksb + 2, 1);
      ld(B, cs, cv, 3);
      ostep(A, ksb + 4, 0);
      const ushort* ns = cs;
      bool nv = cv;
      if (kk < 8) {
        srcp(kk + 1, ns, nv);
        ld(A, ns, nv, 0);
      }
      ostep(B, ksb + 6, 1);
      cs = ns;
      cv = nv;
    }
    int pixcol = (pixf << 4) + (lane & 15);
#pragma unroll
    for (int j = 0; j < 4; ++j) {
      int oc = (ocf << 4) + ((lane >> 4) << 2) + j;
      if (oc < 18) s_off[pixcol][oc] = aoff[j] + b_off[oc];
    }
  }
  __syncthreads();

  // ======== phase 2: bilinear geometry ========
  for (int e = t; e < 576; e += 512) {
    int pix = e & 63, kk = e >> 6;
    int ky = kk / 3, kx = kk - ky * 3;
    float dy = s_off[pix][2 * kk], dx = s_off[pix][2 * kk + 1];
    float py = (float)(ho - 1 + ky) + dy;
    float px = (float)(pix - 1 + kx) + dx;
    float y0f = floorf(py), x0f = floorf(px);
    float ly = py - y0f, lx = px - x0f;
    int y0 = (int)y0f, x0 = (int)x0f;
    int y1 = y0 + 1, x1 = x0 + 1;
    float vy0 = (y0 >= 0 && y0 < 64) ? 1.f : 0.f;
    float vy1 = (y1 >= 0 && y1 < 64) ? 1.f : 0.f;
    float vx0 = (x0 >= 0 && x0 < 64) ? 1.f : 0.f;
    float vx1 = (x1 >= 0 && x1 < 64) ? 1.f : 0.f;
    int cy0 = min(max(y0, 0), 63) << 6, cy1 = min(max(y1, 0), 63) << 6;
    int cx0 = min(max(x0, 0), 63), cx1 = min(max(x1, 0), 63);
    s_gi[kk][pix] = make_int4((cy0 + cx0) << 8, (cy0 + cx1) << 8,
                              (cy1 + cx0) << 8, (cy1 + cx1) << 8);
    s_gw[kk][pix] = make_float4((1.f - ly) * (1.f - lx) * vy0 * vx0,
                                (1.f - ly) * lx * vy0 * vx1,
                                ly * (1.f - lx) * vy1 * vx0,
                                ly * lx * vy1 * vx1);
  }
  __syncthreads();

  // ======== phase 3: main loop (R13 deform10 verbatim) ========
  float4v acc[2][4];
#pragma unroll
  for (int a = 0; a < 2; ++a)
#pragma unroll
    for (int b = 0; b < 4; ++b) acc[a][b] = (float4v)0.f;

  uint4 TA[4], TB[4];

  auto issue = [&](uint4 (&T)[4], int kk, int cg) {
    int4 g = s_gi[kk][p];
    int cb = (cg << 6) + (coct << 3);
    T[0] = *reinterpret_cast<const uint4*>(xTn + g.x + cb);
    T[1] = *reinterpret_cast<const uint4*>(xTn + g.y + cb);
    T[2] = *reinterpret_cast<const uint4*>(xTn + g.z + cb);
    T[3] = *reinterpret_cast<const uint4*>(xTn + g.w + cb);
  };

  auto step = [&](uint4 (&T)[4], int kk, int ks0, int buf) {
    short8v wf[2][2];
#pragma unroll
    for (int ks2 = 0; ks2 < 2; ++ks2)
#pragma unroll
      for (int mf = 0; mf < 2; ++mf)
        wf[ks2][mf] = *reinterpret_cast<const short8v*>(
            &wB[(((size_t)((ks0 + ks2) * 16 + (wave << 1) + mf)) * 64 + lane) * 8]);
    float4 w = s_gw[kk][p];
    uint4 r;
    r.x = bilin_pack(T[0].x, T[1].x, T[2].x, T[3].x, w.x, w.y, w.z, w.w);
    r.y = bilin_pack(T[0].y, T[1].y, T[2].y, T[3].y, w.x, w.y, w.z, w.w);
    r.z = bilin_pack(T[0].z, T[1].z, T[2].z, T[3].z, w.x, w.y, w.z, w.w);
    r.w = bilin_pack(T[0].w, T[1].w, T[2].w, T[3].w, w.x, w.y, w.z, w.w);
    *reinterpret_cast<uint4*>(&s_val[buf][p * 64 + ((coct ^ (p & 7)) << 3)]) = r;
    asm volatile("s_waitcnt lgkmcnt(0)" ::: "memory");
    __builtin_amdgcn_s_barrier();
    __builtin_amdgcn_s_setprio(1);
#pragma unroll
    for (int ks2 = 0; ks2 < 2; ++ks2) {
#pragma unroll
      for (int pf = 0; pf < 4; ++pf) {
        int row = (pf << 4) + (lane & 15);
        int g = (ks2 << 2) + (lane >> 4);
        int slot = g ^ (row & 7);
        short8v vf = *reinterpret_cast<const short8v*>(&s_val[buf][row * 64 + slot * 8]);
#pragma unroll
        for (int mf = 0; mf < 2; ++mf)
          acc[mf][pf] = __builtin_amdgcn_mfma_f32_16x16x32_bf16(
              wf[ks2][mf], vf, acc[mf][pf], 0, 0, 0);
      }
    }
    __builtin_amdgcn_s_setprio(0);
  };

  issue(TA, 0, 0);
  for (int kk = 0; kk < 9; ++kk) {
    int ks0 = kk << 3;
    issue(TB, kk, 1);
    step(TA, kk, ks0 + 0, 0);
    issue(TA, kk, 2);
    step(TB, kk, ks0 + 2, 1);
    issue(TB, kk, 3);
    step(TA, kk, ks0 + 4, 0);
    if (kk < 8) issue(TA, kk + 1, 0);
    step(TB, kk, ks0 + 6, 1);
  }

  // ======== epilogue A: BN partials (relaxed agent stores) ========
  float s[2][4], q[2][4];
#pragma unroll
  for (int mf = 0; mf < 2; ++mf)
#pragma unroll
    for (int j = 0; j < 4; ++j) {
      float ss = 0.f, qq = 0.f;
#pragma unroll
      for (int pf = 0; pf < 4; ++pf) {
        float v = acc[mf][pf][j];
        ss += v;
        qq += v * v;
      }
      s[mf][j] = ss;
      q[mf][j] = qq;
    }
#pragma unroll
  for (int o = 1; o < 16; o <<= 1) {
#pragma unroll
    for (int mf = 0; mf < 2; ++mf)
#pragma unroll
      for (int j = 0; j < 4; ++j) {
        s[mf][j] += __shfl_xor(s[mf][j], o);
        q[mf][j] += __shfl_xor(q[mf][j], o);
      }
  }
  if ((lane & 15) == 0) {
#pragma unroll
    for (int mf = 0; mf < 2; ++mf)
#pragma unroll
      for (int j = 0; j < 4; ++j) {
        int oc = (wave << 5) + (mf << 4) + ((lane >> 4) << 2) + j;
        size_t idx = (size_t)oc * 512 + bid;
        RX_STORE(&partS[idx], s[mf][j]);
        RX_STORE(&partQ[idx], q[mf][j]);
      }
  }

  grid_bar(&bar[0], &bar[32], 1u);

  // ======== epilogue B: stats (blocks 0..255, one oc each) ========
  if (bid < 256) {
    int oc = bid;
    float ss = RX_LOAD(&partS[(size_t)oc * 512 + t]);
    float qq = RX_LOAD(&partQ[(size_t)oc * 512 + t]);
#pragma unroll
    for (int o = 32; o; o >>= 1) {
      ss += __shfl_down(ss, o);
      qq += __shfl_down(qq, o);
    }
    if (lane == 0) s_red[wave] = make_float2(ss, qq);
    __syncthreads();
    if (t == 0) {
      float S = 0.f, Q = 0.f;
#pragma unroll
      for (int i = 0; i < 8; ++i) {
        S += s_red[i].x;
        Q += s_red[i].y;
      }
      float mean = S / 32768.f;
      float var = Q / 32768.f - mean * mean;
      RX_STORE(&statsM[oc], mean);
      RX_STORE(&statsR[oc], rsqrtf(var + 1e-5f));
    }
  }

  grid_bar(&bar[16], &bar[32], 2u);

  // ======== epilogue C: stage stats in LDS, BN+SiLU, final write ========
  float* s_st = &s_off[0][0];   // reuse: [0..255]=mean, [256..511]=rstd
  if (t < 256) {
    s_st[t] = RX_LOAD(&statsM[t]);
    s_st[256 + t] = RX_LOAD(&statsR[t]);
  }
  __syncthreads();
#pragma unroll
  for (int mf = 0; mf < 2; ++mf) {
    int ocb = (wave << 5) + (mf << 4) + ((lane >> 4) << 2);
#pragma unroll
    for (int j = 0; j < 4; ++j) {
      int oc = ocb + j;
      float g = gamma[oc] * s_st[256 + oc];
      float bb = beta[oc] - s_st[oc] * g;
      float* op = out + (((size_t)(n * 256 + oc)) * 64 + ho) * 64;
#pragma unroll
      for (int pf = 0; pf < 4; ++pf) {
        int wo = (pf << 4) + (lane & 15);
        float y = acc[mf][pf][j] * g + bb;
        op[wo] = y / (1.f + expf(-y));
      }
    }
  }
}

extern "C" void kernel_launch(void* const* d_in, const int* in_sizes, int n_in,
                              void* d_out, int out_size, void* d_ws, size_t ws_size,
                              hipStream_t stream) {
  const float* x      = (const float*)d_in[0];
  const float* w_off  = (const float*)d_in[1];
  const float* b_off  = (const float*)d_in[2];
  const float* w_conv = (const float*)d_in[3];
  const float* gamma  = (const float*)d_in[4];
  const float* beta   = (const float*)d_in[5];
  float* out = (float*)d_out;

  float* ws       = (float*)d_ws;
  ushort* ws_xT   = (ushort*)(ws + 589824);           // [8][4096][256] bf16
  ushort* ws_wB   = (ushort*)(ws + 4784128);          // deform weight frags
  ushort* ws_wOB  = (ushort*)(ws + 5079040);          // offset weight frags
  float*  ws_pS   = ws + 5115904;                     // [256][512] f32
  float*  ws_pQ   = ws + 5246976;                     // [256][512] f32
  float*  ws_sM   = ws + 5378048;                     // [256] f32
  float*  ws_sR   = ws + 5378304;                     // [256] f32
  unsigned* ws_bar = (unsigned*)(ws + 5378560);       // 64 u32 barrier area

  (void)hipMemsetAsync(ws_bar, 0, 64 * sizeof(unsigned), stream);
  k_tx_prep<<<836, 256, 0, stream>>>(x, w_conv, w_off, ws_xT, ws_wB, ws_wOB);
  k_dfull<<<512, 512, 0, stream>>>(ws_xT, ws_wB, ws_wOB, b_off, gamma, beta,
                                   out, ws_pS, ws_pQ, ws_sM, ws_sR, ws_bar);
}

// Round 22
// 121.787 us; speedup vs baseline: 9.9613x; 1.0048x over previous
//
#include <hip/hip_runtime.h>
#include <math.h>

#define HW 4096
#define KTOT 2304   // 256 * 9

typedef __attribute__((ext_vector_type(8))) short short8v;
typedef __attribute__((ext_vector_type(4))) float float4v;

__device__ __forceinline__ unsigned int bf16rne(float f) {
  unsigned int x = __float_as_uint(f);
  return (x + 0x7fffu + ((x >> 16) & 1u)) >> 16;
}

__device__ __forceinline__ unsigned int cvtpk(float lo, float hi) {
  unsigned int r;
  asm("v_cvt_pk_bf16_f32 %0, %1, %2" : "=v"(r) : "v"(lo), "v"(hi));
  return r;
}

__device__ __forceinline__ unsigned int bilin_pack(unsigned int u0, unsigned int u1,
                                                   unsigned int u2, unsigned int u3,
                                                   float w0, float w1, float w2, float w3) {
  float lo = w0 * __uint_as_float(u0 << 16) + w1 * __uint_as_float(u1 << 16) +
             w2 * __uint_as_float(u2 << 16) + w3 * __uint_as_float(u3 << 16);
  float hi = w0 * __uint_as_float(u0 & 0xFFFF0000u) + w1 * __uint_as_float(u1 & 0xFFFF0000u) +
             w2 * __uint_as_float(u2 & 0xFFFF0000u) + w3 * __uint_as_float(u3 & 0xFFFF0000u);
  return cvtpk(lo, hi);
}

#define RX_STORE(p, v) __hip_atomic_store((p), (v), __ATOMIC_RELAXED, __HIP_MEMORY_SCOPE_AGENT)
#define RX_LOAD(p)     __hip_atomic_load((p), __ATOMIC_RELAXED, __HIP_MEMORY_SCOPE_AGENT)

// Low-contention grid barrier (grid=512 co-resident by capacity).
// Arrivals: relaxed fetch_add on counter line (memory-side atomics).
// Spin: RELAXED polls on a SEPARATE flag line (no per-poll cache maint).
// One release fence before arrival, one acquire fence after release seen.
__device__ __forceinline__ void grid_bar(unsigned* cnt, unsigned* flag,
                                         unsigned gen) {
  __syncthreads();
  if (threadIdx.x == 0) {
    __builtin_amdgcn_fence(__ATOMIC_RELEASE, "agent");
    unsigned a = __hip_atomic_fetch_add(cnt, 1u, __ATOMIC_RELAXED,
                                        __HIP_MEMORY_SCOPE_AGENT);
    if (a == 511u) {
      __hip_atomic_store(flag, gen, __ATOMIC_RELAXED, __HIP_MEMORY_SCOPE_AGENT);
    } else {
      while (__hip_atomic_load(flag, __ATOMIC_RELAXED,
                               __HIP_MEMORY_SCOPE_AGENT) < gen)
        __builtin_amdgcn_s_sleep(8);
    }
    __builtin_amdgcn_fence(__ATOMIC_ACQUIRE, "agent");
  }
  __syncthreads();
}

// ------------------------------------------------------------------
// ws layout (float offsets):
//   589824   : xT       [8][4096][256] bf16
//   4784128  : wB       [72][16][64][8] bf16
//   5079040  : wOffB    [72][2][64][8] bf16
//   5115904  : partS    [256 oc][512] f32
//   5246976  : partQ    [256 oc][512] f32
//   5378048  : statsM   [256] f32
//   5378304  : statsR   [256] f32
//   5378560  : barrier area (64 u32: cnt0 @0, cnt1 @16, flag @32)
// ------------------------------------------------------------------

// Merged: blocks [0,512) transpose x -> NHWC bf16 via LDS (coalesced both
// sides; n = bid&7 XCD-aligned); [512,800) pack w_conv; [800,836) w_offset.
__global__ __launch_bounds__(256) void k_tx_prep(const float* __restrict__ x,
                                                 const float* __restrict__ wc,
                                                 const float* __restrict__ wo,
                                                 ushort* __restrict__ xT,
                                                 ushort* __restrict__ wB,
                                                 ushort* __restrict__ wOB) {
  __shared__ unsigned s32[64 * 129];   // 33 KB, pad-129 -> conflict-free
  int bid = blockIdx.x;
  if (bid < 512) {
    int n = bid & 7, p0 = (bid >> 3) << 6;
    int t = threadIdx.x;
    int pixr = t & 63;
    int cq = t >> 6;
    const float* xb = x + ((size_t)n * 256) * HW + p0 + pixr;
#pragma unroll 4
    for (int g = 0; g < 32; ++g) {
      int c0 = (g << 3) + (cq << 1);
      float v0 = xb[(size_t)c0 * HW];
      float v1 = xb[(size_t)(c0 + 1) * HW];
      s32[pixr * 129 + (c0 >> 1)] = cvtpk(v0, v1);
    }
    __syncthreads();
    int cslot = t & 31;
    int pw = t >> 5;
#pragma unroll
    for (int pass = 0; pass < 8; ++pass) {
      int pix = (pass << 3) + pw;
      uint4 v = *reinterpret_cast<const uint4*>(&s32[pix * 129 + (cslot << 2)]);
      *reinterpret_cast<uint4*>(
          &xT[((size_t)(n * 4096 + p0 + pix)) * 256 + (cslot << 3)]) = v;
    }
  } else if (bid < 800) {
    int t = (bid - 512) * 256 + threadIdx.x;   // 73728
    int ks = t >> 10;
    int l = t & 63;
    int of = (t >> 6) & 15;
    int kk = ks >> 3;
    int cbase = ((ks & 7) << 5) + ((l >> 4) << 3);
    int oc = (of << 4) + (l & 15);
    unsigned int u[8];
#pragma unroll
    for (int j = 0; j < 8; ++j)
      u[j] = bf16rne(wc[(size_t)oc * KTOT + (size_t)(cbase + j) * 9 + kk]);
    *reinterpret_cast<uint4*>(&wB[(size_t)t * 8]) =
        make_uint4(u[0] | (u[1] << 16), u[2] | (u[3] << 16),
                   u[4] | (u[5] << 16), u[6] | (u[7] << 16));
  } else {
    int t = (bid - 800) * 256 + threadIdx.x;   // 9216
    int ks = t >> 7;
    int l = t & 63;
    int of = (t >> 6) & 1;
    int kk = ks >> 3;
    int cbase = ((ks & 7) << 5) + ((l >> 4) << 3);
    int oc = (of << 4) + (l & 15);
    unsigned int u[8];
#pragma unroll
    for (int j = 0; j < 8; ++j)
      u[j] = (oc < 18) ? bf16rne(wo[(size_t)oc * KTOT + (size_t)(cbase + j) * 9 + kk]) : 0u;
    *reinterpret_cast<uint4*>(&wOB[(size_t)t * 8]) =
        make_uint4(u[0] | (u[1] << 16), u[2] | (u[3] << 16),
                   u[4] | (u[5] << 16), u[6] | (u[7] << 16));
  }
}

// ------------------------------------------------------------------
// FULLY FUSED: offset conv + deformable conv + BN stats + BN+SiLU apply.
// Plain launch, grid 512 x 512 thr, low-contention grid barrier.
// Cross-block data via relaxed agent atomics (coherence point), ordered
// by the barrier's release/acquire fences.
// ------------------------------------------------------------------
__global__ __launch_bounds__(512, 4) void k_dfull(
    const ushort* __restrict__ xT, const ushort* __restrict__ wB,
    const ushort* __restrict__ wOB, const float* __restrict__ b_off,
    const float* __restrict__ gamma, const float* __restrict__ beta,
    float* __restrict__ out, float* __restrict__ partS,
    float* __restrict__ partQ, float* __restrict__ statsM,
    float* __restrict__ statsR, unsigned* __restrict__ bar) {
  __shared__ ushort s_val[2][64 * 64];   // 16 KB
  __shared__ int4   s_gi[9][64];         // 9.2 KB
  __shared__ float4 s_gw[9][64];         // 9.2 KB
  __shared__ float  s_off[64][20];       // 5 KB (reused as stats stage)
  __shared__ float2 s_red[8];

  int bid = blockIdx.x;
  int n = bid & 7, ho = bid >> 3;
  int t = threadIdx.x;
  int lane = t & 63, wave = t >> 6;
  int coct = lane & 7;
  int p = (wave << 3) + (lane >> 3);

  const ushort* xTn = xT + (size_t)n * 4096 * 256;

  // ======== phase 1: offset conv (64 pix x 18 oc) ========
  {
    int ocf = wave & 1, pixf = wave >> 1;
    float4v aoff = (float4v)0.f;

    auto srcp = [&](int kk, const ushort*& s, bool& v) {
      int ky = kk / 3, kx = kk - ky * 3;
      int oy = ho + ky - 1, ox = p + kx - 1;
      v = (oy >= 0) & (oy < 64) & (ox >= 0) & (ox < 64);
      s = xTn + (size_t)(oy * 64 + ox) * 256 + (coct << 3);
    };
    auto ld = [&](uint4& a, const ushort* s, bool v, int cg) {
      a = v ? *reinterpret_cast<const uint4*>(s + (cg << 6)) : make_uint4(0, 0, 0, 0);
    };
    auto ostep = [&](uint4 a, int ksb, int buf) {
      short8v wf[2];
#pragma unroll
      for (int ks2 = 0; ks2 < 2; ++ks2)
        wf[ks2] = *reinterpret_cast<const short8v*>(
            &wOB[(((size_t)((ksb + ks2) * 2 + ocf)) * 64 + lane) * 8]);
      *reinterpret_cast<uint4*>(&s_val[buf][p * 64 + ((coct ^ (p & 7)) << 3)]) = a;
      asm volatile("s_waitcnt lgkmcnt(0)" ::: "memory");
      __builtin_amdgcn_s_barrier();
#pragma unroll
      for (int ks2 = 0; ks2 < 2; ++ks2) {
        int row = (pixf << 4) + (lane & 15);
        int g = (ks2 << 2) + (lane >> 4);
        int slot = g ^ (row & 7);
        short8v vf = *reinterpret_cast<const short8v*>(&s_val[buf][row * 64 + slot * 8]);
        aoff = __builtin_amdgcn_mfma_f32_16x16x32_bf16(wf[ks2], vf, aoff, 0, 0, 0);
      }
    };

    const ushort* cs;
    bool cv;
    srcp(0, cs, cv);
    uint4 A, B;
    ld(A, cs, cv, 0);
    for (int kk = 0; kk < 9; ++kk) {
      int ksb = kk << 3;
      ld(B, cs, cv, 1);
      ostep(A, ksb + 0, 0);
      ld(A, cs, cv, 2);
      ostep(B, ksb + 2, 1);
      ld(B, cs, cv, 3);
      ostep(A, ksb + 4, 0);
      const ushort* ns = cs;
      bool nv = cv;
      if (kk < 8) {
        srcp(kk + 1, ns, nv);
        ld(A, ns, nv, 0);
      }
      ostep(B, ksb + 6, 1);
      cs = ns;
      cv = nv;
    }
    int pixcol = (pixf << 4) + (lane & 15);
#pragma unroll
    for (int j = 0; j < 4; ++j) {
      int oc = (ocf << 4) + ((lane >> 4) << 2) + j;
      if (oc < 18) s_off[pixcol][oc] = aoff[j] + b_off[oc];
    }
  }
  __syncthreads();

  // ======== phase 2: bilinear geometry ========
  for (int e = t; e < 576; e += 512) {
    int pix = e & 63, kk = e >> 6;
    int ky = kk / 3, kx = kk - ky * 3;
    float dy = s_off[pix][2 * kk], dx = s_off[pix][2 * kk + 1];
    float py = (float)(ho - 1 + ky) + dy;
    float px = (float)(pix - 1 + kx) + dx;
    float y0f = floorf(py), x0f = floorf(px);
    float ly = py - y0f, lx = px - x0f;
    int y0 = (int)y0f, x0 = (int)x0f;
    int y1 = y0 + 1, x1 = x0 + 1;
    float vy0 = (y0 >= 0 && y0 < 64) ? 1.f : 0.f;
    float vy1 = (y1 >= 0 && y1 < 64) ? 1.f : 0.f;
    float vx0 = (x0 >= 0 && x0 < 64) ? 1.f : 0.f;
    float vx1 = (x1 >= 0 && x1 < 64) ? 1.f : 0.f;
    int cy0 = min(max(y0, 0), 63) << 6, cy1 = min(max(y1, 0), 63) << 6;
    int cx0 = min(max(x0, 0), 63), cx1 = min(max(x1, 0), 63);
    s_gi[kk][pix] = make_int4((cy0 + cx0) << 8, (cy0 + cx1) << 8,
                              (cy1 + cx0) << 8, (cy1 + cx1) << 8);
    s_gw[kk][pix] = make_float4((1.f - ly) * (1.f - lx) * vy0 * vx0,
                                (1.f - ly) * lx * vy0 * vx1,
                                ly * (1.f - lx) * vy1 * vx0,
                                ly * lx * vy1 * vx1);
  }
  __syncthreads();

  // ======== phase 3: main loop (R13 deform10 verbatim) ========
  float4v acc[2][4];
#pragma unroll
  for (int a = 0; a < 2; ++a)
#pragma unroll
    for (int b = 0; b < 4; ++b) acc[a][b] = (float4v)0.f;

  uint4 TA[4], TB[4];

  auto issue = [&](uint4 (&T)[4], int kk, int cg) {
    int4 g = s_gi[kk][p];
    int cb = (cg << 6) + (coct << 3);
    T[0] = *reinterpret_cast<const uint4*>(xTn + g.x + cb);
    T[1] = *reinterpret_cast<const uint4*>(xTn + g.y + cb);
    T[2] = *reinterpret_cast<const uint4*>(xTn + g.z + cb);
    T[3] = *reinterpret_cast<const uint4*>(xTn + g.w + cb);
  };

  auto step = [&](uint4 (&T)[4], int kk, int ks0, int buf) {
    short8v wf[2][2];
#pragma unroll
    for (int ks2 = 0; ks2 < 2; ++ks2)
#pragma unroll
      for (int mf = 0; mf < 2; ++mf)
        wf[ks2][mf] = *reinterpret_cast<const short8v*>(
            &wB[(((size_t)((ks0 + ks2) * 16 + (wave << 1) + mf)) * 64 + lane) * 8]);
    float4 w = s_gw[kk][p];
    uint4 r;
    r.x = bilin_pack(T[0].x, T[1].x, T[2].x, T[3].x, w.x, w.y, w.z, w.w);
    r.y = bilin_pack(T[0].y, T[1].y, T[2].y, T[3].y, w.x, w.y, w.z, w.w);
    r.z = bilin_pack(T[0].z, T[1].z, T[2].z, T[3].z, w.x, w.y, w.z, w.w);
    r.w = bilin_pack(T[0].w, T[1].w, T[2].w, T[3].w, w.x, w.y, w.z, w.w);
    *reinterpret_cast<uint4*>(&s_val[buf][p * 64 + ((coct ^ (p & 7)) << 3)]) = r;
    asm volatile("s_waitcnt lgkmcnt(0)" ::: "memory");
    __builtin_amdgcn_s_barrier();
    __builtin_amdgcn_s_setprio(1);
#pragma unroll
    for (int ks2 = 0; ks2 < 2; ++ks2) {
#pragma unroll
      for (int pf = 0; pf < 4; ++pf) {
        int row = (pf << 4) + (lane & 15);
        int g = (ks2 << 2) + (lane >> 4);
        int slot = g ^ (row & 7);
        short8v vf = *reinterpret_cast<const short8v*>(&s_val[buf][row * 64 + slot * 8]);
#pragma unroll
        for (int mf = 0; mf < 2; ++mf)
          acc[mf][pf] = __builtin_amdgcn_mfma_f32_16x16x32_bf16(
              wf[ks2][mf], vf, acc[mf][pf], 0, 0, 0);
      }
    }
    __builtin_amdgcn_s_setprio(0);
  };

  issue(TA, 0, 0);
  for (int kk = 0; kk < 9; ++kk) {
    int ks0 = kk << 3;
    issue(TB, kk, 1);
    step(TA, kk, ks0 + 0, 0);
    issue(TA, kk, 2);
    step(TB, kk, ks0 + 2, 1);
    issue(TB, kk, 3);
    step(TA, kk, ks0 + 4, 0);
    if (kk < 8) issue(TA, kk + 1, 0);
    step(TB, kk, ks0 + 6, 1);
  }

  // ======== epilogue A: BN partials (relaxed agent stores) ========
  float s[2][4], q[2][4];
#pragma unroll
  for (int mf = 0; mf < 2; ++mf)
#pragma unroll
    for (int j = 0; j < 4; ++j) {
      float ss = 0.f, qq = 0.f;
#pragma unroll
      for (int pf = 0; pf < 4; ++pf) {
        float v = acc[mf][pf][j];
        ss += v;
        qq += v * v;
      }
      s[mf][j] = ss;
      q[mf][j] = qq;
    }
#pragma unroll
  for (int o = 1; o < 16; o <<= 1) {
#pragma unroll
    for (int mf = 0; mf < 2; ++mf)
#pragma unroll
      for (int j = 0; j < 4; ++j) {
        s[mf][j] += __shfl_xor(s[mf][j], o);
        q[mf][j] += __shfl_xor(q[mf][j], o);
      }
  }
  if ((lane & 15) == 0) {
#pragma unroll
    for (int mf = 0; mf < 2; ++mf)
#pragma unroll
      for (int j = 0; j < 4; ++j) {
        int oc = (wave << 5) + (mf << 4) + ((lane >> 4) << 2) + j;
        size_t idx = (size_t)oc * 512 + bid;
        RX_STORE(&partS[idx], s[mf][j]);
        RX_STORE(&partQ[idx], q[mf][j]);
      }
  }

  grid_bar(&bar[0], &bar[32], 1u);

  // ======== epilogue B: stats (blocks 0..255, one oc each) ========
  if (bid < 256) {
    int oc = bid;
    float ss = RX_LOAD(&partS[(size_t)oc * 512 + t]);
    float qq = RX_LOAD(&partQ[(size_t)oc * 512 + t]);
#pragma unroll
    for (int o = 32; o; o >>= 1) {
      ss += __shfl_down(ss, o);
      qq += __shfl_down(qq, o);
    }
    if (lane == 0) s_red[wave] = make_float2(ss, qq);
    __syncthreads();
    if (t == 0) {
      float S = 0.f, Q = 0.f;
#pragma unroll
      for (int i = 0; i < 8; ++i) {
        S += s_red[i].x;
        Q += s_red[i].y;
      }
      float mean = S / 32768.f;
      float var = Q / 32768.f - mean * mean;
      RX_STORE(&statsM[oc], mean);
      RX_STORE(&statsR[oc], rsqrtf(var + 1e-5f));
    }
  }

  grid_bar(&bar[16], &bar[32], 2u);

  // ======== epilogue C: stage stats in LDS, BN+SiLU, final write ========
  float* s_st = &s_off[0][0];   // reuse: [0..255]=mean, [256..511]=rstd
  if (t < 256) {
    s_st[t] = RX_LOAD(&statsM[t]);
    s_st[256 + t] = RX_LOAD(&statsR[t]);
  }
  __syncthreads();
#pragma unroll
  for (int mf = 0; mf < 2; ++mf) {
    int ocb = (wave << 5) + (mf << 4) + ((lane >> 4) << 2);
#pragma unroll
    for (int j = 0; j < 4; ++j) {
      int oc = ocb + j;
      float g = gamma[oc] * s_st[256 + oc];
      float bb = beta[oc] - s_st[oc] * g;
      float* op = out + (((size_t)(n * 256 + oc)) * 64 + ho) * 64;
#pragma unroll
      for (int pf = 0; pf < 4; ++pf) {
        int wo = (pf << 4) + (lane & 15);
        float y = acc[mf][pf][j] * g + bb;
        op[wo] = y / (1.f + expf(-y));
      }
    }
  }
}

extern "C" void kernel_launch(void* const* d_in, const int* in_sizes, int n_in,
                              void* d_out, int out_size, void* d_ws, size_t ws_size,
                              hipStream_t stream) {
  const float* x      = (const float*)d_in[0];
  const float* w_off  = (const float*)d_in[1];
  const float* b_off  = (const float*)d_in[2];
  const float* w_conv = (const float*)d_in[3];
  const float* gamma  = (const float*)d_in[4];
  const float* beta   = (const float*)d_in[5];
  float* out = (float*)d_out;

  float* ws       = (float*)d_ws;
  ushort* ws_xT   = (ushort*)(ws + 589824);           // [8][4096][256] bf16
  ushort* ws_wB   = (ushort*)(ws + 4784128);          // deform weight frags
  ushort* ws_wOB  = (ushort*)(ws + 5079040);          // offset weight frags
  float*  ws_pS   = ws + 5115904;                     // [256][512] f32
  float*  ws_pQ   = ws + 5246976;                     // [256][512] f32
  float*  ws_sM   = ws + 5378048;                     // [256] f32
  float*  ws_sR   = ws + 5378304;                     // [256] f32
  unsigned* ws_bar = (unsigned*)(ws + 5378560);       // 64 u32 barrier area

  (void)hipMemsetAsync(ws_bar, 0, 64 * sizeof(unsigned), stream);
  k_tx_prep<<<836, 256, 0, stream>>>(x, w_conv, w_off, ws_xT, ws_wB, ws_wOB);
  k_dfull<<<512, 512, 0, stream>>>(ws_xT, ws_wB, ws_wOB, b_off, gamma, beta,
                                   out, ws_pS, ws_pQ, ws_sM, ws_sR, ws_bar);
}

// Round 23
// 103.103 us; speedup vs baseline: 11.7664x; 1.1812x over previous
//
#include <hip/hip_runtime.h>
#include <math.h>

#define HW 4096
#define KTOT 2304   // 256 * 9

typedef __attribute__((ext_vector_type(8))) short short8v;
typedef __attribute__((ext_vector_type(4))) float float4v;

__device__ __forceinline__ unsigned int bf16rne(float f) {
  unsigned int x = __float_as_uint(f);
  return (x + 0x7fffu + ((x >> 16) & 1u)) >> 16;
}

__device__ __forceinline__ unsigned int cvtpk(float lo, float hi) {
  unsigned int r;
  asm("v_cvt_pk_bf16_f32 %0, %1, %2" : "=v"(r) : "v"(lo), "v"(hi));
  return r;
}

__device__ __forceinline__ unsigned int bilin_pack(unsigned int u0, unsigned int u1,
                                                   unsigned int u2, unsigned int u3,
                                                   float w0, float w1, float w2, float w3) {
  float lo = w0 * __uint_as_float(u0 << 16) + w1 * __uint_as_float(u1 << 16) +
             w2 * __uint_as_float(u2 << 16) + w3 * __uint_as_float(u3 << 16);
  float hi = w0 * __uint_as_float(u0 & 0xFFFF0000u) + w1 * __uint_as_float(u1 & 0xFFFF0000u) +
             w2 * __uint_as_float(u2 & 0xFFFF0000u) + w3 * __uint_as_float(u3 & 0xFFFF0000u);
  return cvtpk(lo, hi);
}

// ------------------------------------------------------------------
// ws layout (float offsets):
//   589824   : xT       [8][4096][256] bf16
//   4784128  : wB       [72][16][64][8] bf16
//   5079040  : wOffB    [72][2][64][8] bf16
//   5115904  : part     [256 oc][512] float2
//   5378048  : stats    [256] float2
// ------------------------------------------------------------------

// Merged: blocks [0,512) transpose x -> NHWC bf16 via LDS (coalesced both
// sides; n = bid&7 XCD-aligned); [512,800) pack w_conv; [800,836) w_offset.
__global__ __launch_bounds__(256) void k_tx_prep(const float* __restrict__ x,
                                                 const float* __restrict__ wc,
                                                 const float* __restrict__ wo,
                                                 ushort* __restrict__ xT,
                                                 ushort* __restrict__ wB,
                                                 ushort* __restrict__ wOB) {
  __shared__ unsigned s32[64 * 129];   // 33 KB, pad-129 -> conflict-free
  int bid = blockIdx.x;
  if (bid < 512) {
    int n = bid & 7, p0 = (bid >> 3) << 6;
    int t = threadIdx.x;
    int pixr = t & 63;
    int cq = t >> 6;
    const float* xb = x + ((size_t)n * 256) * HW + p0 + pixr;
#pragma unroll 4
    for (int g = 0; g < 32; ++g) {
      int c0 = (g << 3) + (cq << 1);
      float v0 = xb[(size_t)c0 * HW];
      float v1 = xb[(size_t)(c0 + 1) * HW];
      s32[pixr * 129 + (c0 >> 1)] = cvtpk(v0, v1);
    }
    __syncthreads();
    int cslot = t & 31;
    int pw = t >> 5;
#pragma unroll
    for (int pass = 0; pass < 8; ++pass) {
      int pix = (pass << 3) + pw;
      uint4 v = *reinterpret_cast<const uint4*>(&s32[pix * 129 + (cslot << 2)]);
      *reinterpret_cast<uint4*>(
          &xT[((size_t)(n * 4096 + p0 + pix)) * 256 + (cslot << 3)]) = v;
    }
  } else if (bid < 800) {
    int t = (bid - 512) * 256 + threadIdx.x;   // 73728
    int ks = t >> 10;
    int l = t & 63;
    int of = (t >> 6) & 15;
    int kk = ks >> 3;
    int cbase = ((ks & 7) << 5) + ((l >> 4) << 3);
    int oc = (of << 4) + (l & 15);
    unsigned int u[8];
#pragma unroll
    for (int j = 0; j < 8; ++j)
      u[j] = bf16rne(wc[(size_t)oc * KTOT + (size_t)(cbase + j) * 9 + kk]);
    *reinterpret_cast<uint4*>(&wB[(size_t)t * 8]) =
        make_uint4(u[0] | (u[1] << 16), u[2] | (u[3] << 16),
                   u[4] | (u[5] << 16), u[6] | (u[7] << 16));
  } else {
    int t = (bid - 800) * 256 + threadIdx.x;   // 9216
    int ks = t >> 7;
    int l = t & 63;
    int of = (t >> 6) & 1;
    int kk = ks >> 3;
    int cbase = ((ks & 7) << 5) + ((l >> 4) << 3);
    int oc = (of << 4) + (l & 15);
    unsigned int u[8];
#pragma unroll
    for (int j = 0; j < 8; ++j)
      u[j] = (oc < 18) ? bf16rne(wo[(size_t)oc * KTOT + (size_t)(cbase + j) * 9 + kk]) : 0u;
    *reinterpret_cast<uint4*>(&wOB[(size_t)t * 8]) =
        make_uint4(u[0] | (u[1] << 16), u[2] | (u[3] << 16),
                   u[4] | (u[5] << 16), u[6] | (u[7] << 16));
  }
}

// ------------------------------------------------------------------
// FUSED offset conv + deformable conv. Block: 512 thr, (n = bid&7, ho).
// Phase 1: offset conv for this block's 64 pixels -> s_off[64][20].
// Phase 2: bilinear geometry from s_off.
// Phase 3: main implicit-GEMM loop = R13's proven deform10 verbatim.
// ------------------------------------------------------------------
__global__ __launch_bounds__(512, 4) void k_dfull(
    const ushort* __restrict__ xT, const ushort* __restrict__ wB,
    const ushort* __restrict__ wOB, const float* __restrict__ b_off,
    float* __restrict__ out, float2* __restrict__ part) {
  __shared__ ushort s_val[2][64 * 64];   // 16 KB (shared by both phases)
  __shared__ int4   s_gi[9][64];         // 9.2 KB
  __shared__ float4 s_gw[9][64];         // 9.2 KB
  __shared__ float  s_off[64][20];       // 5 KB

  int bid = blockIdx.x;
  int n = bid & 7, ho = bid >> 3;
  int t = threadIdx.x;
  int lane = t & 63, wave = t >> 6;
  int coct = lane & 7;
  int p = (wave << 3) + (lane >> 3);   // 0..63, this thread's pixel

  const ushort* xTn = xT + (size_t)n * 4096 * 256;

  // ======== phase 1: offset conv (64 pix x 18 oc) ========
  {
    int ocf = wave & 1, pixf = wave >> 1;
    float4v aoff = (float4v)0.f;

    auto srcp = [&](int kk, const ushort*& s, bool& v) {
      int ky = kk / 3, kx = kk - ky * 3;
      int oy = ho + ky - 1, ox = p + kx - 1;
      v = (oy >= 0) & (oy < 64) & (ox >= 0) & (ox < 64);
      s = xTn + (size_t)(oy * 64 + ox) * 256 + (coct << 3);
    };
    auto ld = [&](uint4& a, const ushort* s, bool v, int cg) {
      a = v ? *reinterpret_cast<const uint4*>(s + (cg << 6)) : make_uint4(0, 0, 0, 0);
    };
    auto ostep = [&](uint4 a, int ksb, int buf) {
      short8v wf[2];
#pragma unroll
      for (int ks2 = 0; ks2 < 2; ++ks2)
        wf[ks2] = *reinterpret_cast<const short8v*>(
            &wOB[(((size_t)((ksb + ks2) * 2 + ocf)) * 64 + lane) * 8]);
      *reinterpret_cast<uint4*>(&s_val[buf][p * 64 + ((coct ^ (p & 7)) << 3)]) = a;
      asm volatile("s_waitcnt lgkmcnt(0)" ::: "memory");
      __builtin_amdgcn_s_barrier();
#pragma unroll
      for (int ks2 = 0; ks2 < 2; ++ks2) {
        int row = (pixf << 4) + (lane & 15);
        int g = (ks2 << 2) + (lane >> 4);
        int slot = g ^ (row & 7);
        short8v vf = *reinterpret_cast<const short8v*>(&s_val[buf][row * 64 + slot * 8]);
        aoff = __builtin_amdgcn_mfma_f32_16x16x32_bf16(wf[ks2], vf, aoff, 0, 0, 0);
      }
    };

    const ushort* cs;
    bool cv;
    srcp(0, cs, cv);
    uint4 A, B;
    ld(A, cs, cv, 0);
    for (int kk = 0; kk < 9; ++kk) {
      int ksb = kk << 3;
      ld(B, cs, cv, 1);
      ostep(A, ksb + 0, 0);
      ld(A, cs, cv, 2);
      ostep(B, ksb + 2, 1);
      ld(B, cs, cv, 3);
      ostep(A, ksb + 4, 0);
      const ushort* ns = cs;
      bool nv = cv;
      if (kk < 8) {
        srcp(kk + 1, ns, nv);
        ld(A, ns, nv, 0);
      }
      ostep(B, ksb + 6, 1);
      cs = ns;
      cv = nv;
    }
    int pixcol = (pixf << 4) + (lane & 15);
#pragma unroll
    for (int j = 0; j < 4; ++j) {
      int oc = (ocf << 4) + ((lane >> 4) << 2) + j;
      if (oc < 18) s_off[pixcol][oc] = aoff[j] + b_off[oc];
    }
  }
  __syncthreads();

  // ======== phase 2: bilinear geometry for all (kk, pix) from s_off ====
  for (int e = t; e < 576; e += 512) {
    int pix = e & 63, kk = e >> 6;
    int ky = kk / 3, kx = kk - ky * 3;
    float dy = s_off[pix][2 * kk], dx = s_off[pix][2 * kk + 1];
    float py = (float)(ho - 1 + ky) + dy;
    float px = (float)(pix - 1 + kx) + dx;
    float y0f = floorf(py), x0f = floorf(px);
    float ly = py - y0f, lx = px - x0f;
    int y0 = (int)y0f, x0 = (int)x0f;
    int y1 = y0 + 1, x1 = x0 + 1;
    float vy0 = (y0 >= 0 && y0 < 64) ? 1.f : 0.f;
    float vy1 = (y1 >= 0 && y1 < 64) ? 1.f : 0.f;
    float vx0 = (x0 >= 0 && x0 < 64) ? 1.f : 0.f;
    float vx1 = (x1 >= 0 && x1 < 64) ? 1.f : 0.f;
    int cy0 = min(max(y0, 0), 63) << 6, cy1 = min(max(y1, 0), 63) << 6;
    int cx0 = min(max(x0, 0), 63), cx1 = min(max(x1, 0), 63);
    s_gi[kk][pix] = make_int4((cy0 + cx0) << 8, (cy0 + cx1) << 8,
                              (cy1 + cx0) << 8, (cy1 + cx1) << 8);
    s_gw[kk][pix] = make_float4((1.f - ly) * (1.f - lx) * vy0 * vx0,
                                (1.f - ly) * lx * vy0 * vx1,
                                ly * (1.f - lx) * vy1 * vx0,
                                ly * lx * vy1 * vx1);
  }
  __syncthreads();

  // ======== phase 3: main loop (R13 deform10 verbatim) ========
  float4v acc[2][4];
#pragma unroll
  for (int a = 0; a < 2; ++a)
#pragma unroll
    for (int b = 0; b < 4; ++b) acc[a][b] = (float4v)0.f;

  uint4 TA[4], TB[4];

  auto issue = [&](uint4 (&T)[4], int kk, int cg) {
    int4 g = s_gi[kk][p];
    int cb = (cg << 6) + (coct << 3);
    T[0] = *reinterpret_cast<const uint4*>(xTn + g.x + cb);
    T[1] = *reinterpret_cast<const uint4*>(xTn + g.y + cb);
    T[2] = *reinterpret_cast<const uint4*>(xTn + g.z + cb);
    T[3] = *reinterpret_cast<const uint4*>(xTn + g.w + cb);
  };

  auto step = [&](uint4 (&T)[4], int kk, int ks0, int buf) {
    short8v wf[2][2];
#pragma unroll
    for (int ks2 = 0; ks2 < 2; ++ks2)
#pragma unroll
      for (int mf = 0; mf < 2; ++mf)
        wf[ks2][mf] = *reinterpret_cast<const short8v*>(
            &wB[(((size_t)((ks0 + ks2) * 16 + (wave << 1) + mf)) * 64 + lane) * 8]);
    float4 w = s_gw[kk][p];
    uint4 r;
    r.x = bilin_pack(T[0].x, T[1].x, T[2].x, T[3].x, w.x, w.y, w.z, w.w);
    r.y = bilin_pack(T[0].y, T[1].y, T[2].y, T[3].y, w.x, w.y, w.z, w.w);
    r.z = bilin_pack(T[0].z, T[1].z, T[2].z, T[3].z, w.x, w.y, w.z, w.w);
    r.w = bilin_pack(T[0].w, T[1].w, T[2].w, T[3].w, w.x, w.y, w.z, w.w);
    *reinterpret_cast<uint4*>(&s_val[buf][p * 64 + ((coct ^ (p & 7)) << 3)]) = r;
    asm volatile("s_waitcnt lgkmcnt(0)" ::: "memory");
    __builtin_amdgcn_s_barrier();
    __builtin_amdgcn_s_setprio(1);
#pragma unroll
    for (int ks2 = 0; ks2 < 2; ++ks2) {
#pragma unroll
      for (int pf = 0; pf < 4; ++pf) {
        int row = (pf << 4) + (lane & 15);
        int g = (ks2 << 2) + (lane >> 4);
        int slot = g ^ (row & 7);
        short8v vf = *reinterpret_cast<const short8v*>(&s_val[buf][row * 64 + slot * 8]);
#pragma unroll
        for (int mf = 0; mf < 2; ++mf)
          acc[mf][pf] = __builtin_amdgcn_mfma_f32_16x16x32_bf16(
              wf[ks2][mf], vf, acc[mf][pf], 0, 0, 0);
      }
    }
    __builtin_amdgcn_s_setprio(0);
  };

  issue(TA, 0, 0);
  for (int kk = 0; kk < 9; ++kk) {
    int ks0 = kk << 3;
    issue(TB, kk, 1);
    step(TA, kk, ks0 + 0, 0);
    issue(TA, kk, 2);
    step(TB, kk, ks0 + 2, 1);
    issue(TB, kk, 3);
    step(TA, kk, ks0 + 4, 0);
    if (kk < 8) issue(TA, kk + 1, 0);
    step(TB, kk, ks0 + 6, 1);
  }

  // ---- epilogue: out NCHW + per-block BN partials ----
#pragma unroll
  for (int mf = 0; mf < 2; ++mf) {
    int ocb = (wave << 5) + (mf << 4) + ((lane >> 4) << 2);
#pragma unroll
    for (int pf = 0; pf < 4; ++pf) {
      int wo = (pf << 4) + (lane & 15);
      float* op = out + (((size_t)(n * 256 + ocb)) * 64 + ho) * 64 + wo;
      float4v a = acc[mf][pf];
      op[0] = a[0];
      op[HW] = a[1];
      op[2 * HW] = a[2];
      op[3 * HW] = a[3];
    }
  }
  float s[2][4], q[2][4];
#pragma unroll
  for (int mf = 0; mf < 2; ++mf)
#pragma unroll
    for (int j = 0; j < 4; ++j) {
      float ss = 0.f, qq = 0.f;
#pragma unroll
      for (int pf = 0; pf < 4; ++pf) {
        float v = acc[mf][pf][j];
        ss += v;
        qq += v * v;
      }
      s[mf][j] = ss;
      q[mf][j] = qq;
    }
#pragma unroll
  for (int o = 1; o < 16; o <<= 1) {
#pragma unroll
    for (int mf = 0; mf < 2; ++mf)
#pragma unroll
      for (int j = 0; j < 4; ++j) {
        s[mf][j] += __shfl_xor(s[mf][j], o);
        q[mf][j] += __shfl_xor(q[mf][j], o);
      }
  }
  if ((lane & 15) == 0) {
#pragma unroll
    for (int mf = 0; mf < 2; ++mf)
#pragma unroll
      for (int j = 0; j < 4; ++j) {
        int oc = (wave << 5) + (mf << 4) + ((lane >> 4) << 2) + j;
        part[(size_t)oc * 512 + bid] = make_float2(s[mf][j], q[mf][j]);
      }
  }
}

__global__ __launch_bounds__(256) void k_stats_fin(const float2* __restrict__ part,
                                                   float2* __restrict__ stats) {
  int oc = blockIdx.x;
  int t = threadIdx.x;
  float2 a = part[(size_t)oc * 512 + t];
  float2 b = part[(size_t)oc * 512 + 256 + t];
  float s = a.x + b.x, q = a.y + b.y;
#pragma unroll
  for (int o = 32; o; o >>= 1) {
    s += __shfl_down(s, o);
    q += __shfl_down(q, o);
  }
  __shared__ float2 wsum[4];
  if ((t & 63) == 0) wsum[t >> 6] = make_float2(s, q);
  __syncthreads();
  if (t == 0) {
    float S = wsum[0].x + wsum[1].x + wsum[2].x + wsum[3].x;
    float Q = wsum[0].y + wsum[1].y + wsum[2].y + wsum[3].y;
    float mean = S / 32768.f;
    float var = Q / 32768.f - mean * mean;
    stats[oc] = make_float2(mean, rsqrtf(var + 1e-5f));
  }
}

// BN+SiLU, XCD-aligned: blocks for image n land on XCD n.
__global__ __launch_bounds__(256) void k_bn_silu(float* __restrict__ out,
                                                 const float2* __restrict__ stats,
                                                 const float* __restrict__ gamma,
                                                 const float* __restrict__ beta) {
  int b = blockIdx.x;
  int nb = (b & 7) * 1024 + (b >> 3);   // image = b&7
  size_t i4 = (size_t)nb * 256 + threadIdx.x;
  int ch = (int)((i4 >> 10) & 255);
  float2 st = stats[ch];
  float g = gamma[ch] * st.y;
  float bb = beta[ch] - st.x * g;
  float4 v = *(float4*)(out + i4 * 4);
  float y0 = v.x * g + bb, y1 = v.y * g + bb, y2 = v.z * g + bb, y3 = v.w * g + bb;
  v.x = y0 / (1.f + expf(-y0));
  v.y = y1 / (1.f + expf(-y1));
  v.z = y2 / (1.f + expf(-y2));
  v.w = y3 / (1.f + expf(-y3));
  *(float4*)(out + i4 * 4) = v;
}

extern "C" void kernel_launch(void* const* d_in, const int* in_sizes, int n_in,
                              void* d_out, int out_size, void* d_ws, size_t ws_size,
                              hipStream_t stream) {
  const float* x      = (const float*)d_in[0];
  const float* w_off  = (const float*)d_in[1];
  const float* b_off  = (const float*)d_in[2];
  const float* w_conv = (const float*)d_in[3];
  const float* gamma  = (const float*)d_in[4];
  const float* beta   = (const float*)d_in[5];
  float* out = (float*)d_out;

  float* ws       = (float*)d_ws;
  ushort* ws_xT   = (ushort*)(ws + 589824);           // [8][4096][256] bf16
  ushort* ws_wB   = (ushort*)(ws + 4784128);          // deform weight frags
  ushort* ws_wOB  = (ushort*)(ws + 5079040);          // offset weight frags
  float2* ws_part = (float2*)(ws + 5115904);          // [256][512] partials
  float2* ws_st   = (float2*)(ws + 5378048);          // [256] stats

  k_tx_prep<<<836, 256, 0, stream>>>(x, w_conv, w_off, ws_xT, ws_wB, ws_wOB);
  k_dfull<<<512, 512, 0, stream>>>(ws_xT, ws_wB, ws_wOB, b_off, out, ws_part);
  k_stats_fin<<<256, 256, 0, stream>>>(ws_part, ws_st);
  k_bn_silu<<<8192, 256, 0, stream>>>(out, ws_st, gamma, beta);
}

// Round 24
// 103.028 us; speedup vs baseline: 11.7750x; 1.0007x over previous
//
#include <hip/hip_runtime.h>
#include <math.h>

#define HW 4096
#define KTOT 2304   // 256 * 9

typedef __attribute__((ext_vector_type(8))) short short8v;
typedef __attribute__((ext_vector_type(4))) float float4v;

__device__ __forceinline__ unsigned int bf16rne(float f) {
  unsigned int x = __float_as_uint(f);
  return (x + 0x7fffu + ((x >> 16) & 1u)) >> 16;
}

__device__ __forceinline__ unsigned int cvtpk(float lo, float hi) {
  unsigned int r;
  asm("v_cvt_pk_bf16_f32 %0, %1, %2" : "=v"(r) : "v"(lo), "v"(hi));
  return r;
}

__device__ __forceinline__ unsigned int bilin_pack(unsigned int u0, unsigned int u1,
                                                   unsigned int u2, unsigned int u3,
                                                   float w0, float w1, float w2, float w3) {
  float lo = w0 * __uint_as_float(u0 << 16) + w1 * __uint_as_float(u1 << 16) +
             w2 * __uint_as_float(u2 << 16) + w3 * __uint_as_float(u3 << 16);
  float hi = w0 * __uint_as_float(u0 & 0xFFFF0000u) + w1 * __uint_as_float(u1 & 0xFFFF0000u) +
             w2 * __uint_as_float(u2 & 0xFFFF0000u) + w3 * __uint_as_float(u3 & 0xFFFF0000u);
  return cvtpk(lo, hi);
}

// ------------------------------------------------------------------
// ws layout (float offsets):
//   589824   : xT       [8][4096][256] bf16
//   4784128  : wB       [72][16][64][8] bf16
//   5079040  : wOffB    [72][2][64][8] bf16
//   5115904  : part     [256 oc][512] float2
//   5378048  : stats    [256] float2
// ------------------------------------------------------------------

// Merged: blocks [0,512) transpose x -> NHWC bf16 via LDS (coalesced both
// sides; n = bid&7 XCD-aligned); [512,800) pack w_conv; [800,836) w_offset.
__global__ __launch_bounds__(256) void k_tx_prep(const float* __restrict__ x,
                                                 const float* __restrict__ wc,
                                                 const float* __restrict__ wo,
                                                 ushort* __restrict__ xT,
                                                 ushort* __restrict__ wB,
                                                 ushort* __restrict__ wOB) {
  __shared__ unsigned s32[64 * 129];   // 33 KB, pad-129 -> conflict-free
  int bid = blockIdx.x;
  if (bid < 512) {
    int n = bid & 7, p0 = (bid >> 3) << 6;
    int t = threadIdx.x;
    int pixr = t & 63;
    int cq = t >> 6;
    const float* xb = x + ((size_t)n * 256) * HW + p0 + pixr;
#pragma unroll 4
    for (int g = 0; g < 32; ++g) {
      int c0 = (g << 3) + (cq << 1);
      float v0 = xb[(size_t)c0 * HW];
      float v1 = xb[(size_t)(c0 + 1) * HW];
      s32[pixr * 129 + (c0 >> 1)] = cvtpk(v0, v1);
    }
    __syncthreads();
    int cslot = t & 31;
    int pw = t >> 5;
#pragma unroll
    for (int pass = 0; pass < 8; ++pass) {
      int pix = (pass << 3) + pw;
      uint4 v = *reinterpret_cast<const uint4*>(&s32[pix * 129 + (cslot << 2)]);
      *reinterpret_cast<uint4*>(
          &xT[((size_t)(n * 4096 + p0 + pix)) * 256 + (cslot << 3)]) = v;
    }
  } else if (bid < 800) {
    int t = (bid - 512) * 256 + threadIdx.x;   // 73728
    int ks = t >> 10;
    int l = t & 63;
    int of = (t >> 6) & 15;
    int kk = ks >> 3;
    int cbase = ((ks & 7) << 5) + ((l >> 4) << 3);
    int oc = (of << 4) + (l & 15);
    unsigned int u[8];
#pragma unroll
    for (int j = 0; j < 8; ++j)
      u[j] = bf16rne(wc[(size_t)oc * KTOT + (size_t)(cbase + j) * 9 + kk]);
    *reinterpret_cast<uint4*>(&wB[(size_t)t * 8]) =
        make_uint4(u[0] | (u[1] << 16), u[2] | (u[3] << 16),
                   u[4] | (u[5] << 16), u[6] | (u[7] << 16));
  } else {
    int t = (bid - 800) * 256 + threadIdx.x;   // 9216
    int ks = t >> 7;
    int l = t & 63;
    int of = (t >> 6) & 1;
    int kk = ks >> 3;
    int cbase = ((ks & 7) << 5) + ((l >> 4) << 3);
    int oc = (of << 4) + (l & 15);
    unsigned int u[8];
#pragma unroll
    for (int j = 0; j < 8; ++j)
      u[j] = (oc < 18) ? bf16rne(wo[(size_t)oc * KTOT + (size_t)(cbase + j) * 9 + kk]) : 0u;
    *reinterpret_cast<uint4*>(&wOB[(size_t)t * 8]) =
        make_uint4(u[0] | (u[1] << 16), u[2] | (u[3] << 16),
                   u[4] | (u[5] << 16), u[6] | (u[7] << 16));
  }
}

// ------------------------------------------------------------------
// FUSED offset conv + deformable conv. Block: 512 thr, (n = bid&7, ho).
// Phase 1: offset conv, 2-chunk phases (18 barriers) -> s_off[64][20].
// Phase 2: bilinear geometry from s_off.
// Phase 3: main implicit-GEMM loop = R13's proven deform10 verbatim.
// ------------------------------------------------------------------
__global__ __launch_bounds__(512, 4) void k_dfull(
    const ushort* __restrict__ xT, const ushort* __restrict__ wB,
    const ushort* __restrict__ wOB, const float* __restrict__ b_off,
    float* __restrict__ out, float2* __restrict__ part) {
  __shared__ ushort s_val[2][64 * 128];  // 32 KB (phase1: [64][128]; phase3 uses first 8 KB/buf)
  __shared__ int4   s_gi[9][64];         // 9.2 KB
  __shared__ float4 s_gw[9][64];         // 9.2 KB
  __shared__ float  s_off[64][20];       // 5 KB

  int bid = blockIdx.x;
  int n = bid & 7, ho = bid >> 3;
  int t = threadIdx.x;
  int lane = t & 63, wave = t >> 6;
  int coct = lane & 7;
  int p = (wave << 3) + (lane >> 3);   // 0..63, this thread's pixel

  const ushort* xTn = xT + (size_t)n * 4096 * 256;

  // ======== phase 1: offset conv (64 pix x 18 oc), 2-chunk phases ========
  {
    int ocf = wave & 1, pixf = wave >> 1;
    float4v aoff = (float4v)0.f;

    auto srcp = [&](int kk, const ushort*& s, bool& v) {
      int ky = kk / 3, kx = kk - ky * 3;
      int oy = ho + ky - 1, ox = p + kx - 1;
      v = (oy >= 0) & (oy < 64) & (ox >= 0) & (ox < 64);
      s = xTn + (size_t)(oy * 64 + ox) * 256 + (coct << 3);
    };
    // load tap pair for chunks (cg0, cg0+1) of this kk
    auto ld2 = [&](uint4& a0, uint4& a1, const ushort* s, bool v, int cg0) {
      a0 = v ? *reinterpret_cast<const uint4*>(s + (cg0 << 6)) : make_uint4(0, 0, 0, 0);
      a1 = v ? *reinterpret_cast<const uint4*>(s + ((cg0 + 1) << 6)) : make_uint4(0, 0, 0, 0);
    };
    // one phase: write 2 chunks, 1 barrier, 4 MFMA ksteps (ksb = 4*ph)
    auto ostep2 = [&](uint4 a0, uint4 a1, int ph, int buf) {
      short8v wf[4];
#pragma unroll
      for (int ks2 = 0; ks2 < 4; ++ks2)
        wf[ks2] = *reinterpret_cast<const short8v*>(
            &wOB[(((size_t)((4 * ph + ks2) * 2 + ocf)) * 64 + lane) * 8]);
      int wslot = (coct ^ (p & 7)) << 3;
      *reinterpret_cast<uint4*>(&s_val[buf][p * 128 + wslot]) = a0;
      *reinterpret_cast<uint4*>(&s_val[buf][p * 128 + 64 + wslot]) = a1;
      asm volatile("s_waitcnt lgkmcnt(0)" ::: "memory");
      __builtin_amdgcn_s_barrier();
#pragma unroll
      for (int ks2 = 0; ks2 < 4; ++ks2) {
        int row = (pixf << 4) + (lane & 15);
        int g = ((ks2 & 1) << 2) + (lane >> 4);
        int slot = g ^ (row & 7);
        int half = ks2 >> 1;
        short8v vf = *reinterpret_cast<const short8v*>(
            &s_val[buf][row * 128 + (half << 6) + slot * 8]);
        aoff = __builtin_amdgcn_mfma_f32_16x16x32_bf16(wf[ks2], vf, aoff, 0, 0, 0);
      }
    };

    const ushort* cs;
    bool cv;
    srcp(0, cs, cv);
    uint4 A0, A1, B0, B1;
    ld2(A0, A1, cs, cv, 0);
    for (int kk = 0; kk < 9; ++kk) {
      ld2(B0, B1, cs, cv, 2);
      ostep2(A0, A1, 2 * kk + 0, 0);
      const ushort* ns = cs;
      bool nv = cv;
      if (kk < 8) {
        srcp(kk + 1, ns, nv);
        ld2(A0, A1, ns, nv, 0);
      }
      ostep2(B0, B1, 2 * kk + 1, 1);
      cs = ns;
      cv = nv;
    }
    int pixcol = (pixf << 4) + (lane & 15);
#pragma unroll
    for (int j = 0; j < 4; ++j) {
      int oc = (ocf << 4) + ((lane >> 4) << 2) + j;
      if (oc < 18) s_off[pixcol][oc] = aoff[j] + b_off[oc];
    }
  }
  __syncthreads();

  // ======== phase 2: bilinear geometry for all (kk, pix) from s_off ====
  for (int e = t; e < 576; e += 512) {
    int pix = e & 63, kk = e >> 6;
    int ky = kk / 3, kx = kk - ky * 3;
    float dy = s_off[pix][2 * kk], dx = s_off[pix][2 * kk + 1];
    float py = (float)(ho - 1 + ky) + dy;
    float px = (float)(pix - 1 + kx) + dx;
    float y0f = floorf(py), x0f = floorf(px);
    float ly = py - y0f, lx = px - x0f;
    int y0 = (int)y0f, x0 = (int)x0f;
    int y1 = y0 + 1, x1 = x0 + 1;
    float vy0 = (y0 >= 0 && y0 < 64) ? 1.f : 0.f;
    float vy1 = (y1 >= 0 && y1 < 64) ? 1.f : 0.f;
    float vx0 = (x0 >= 0 && x0 < 64) ? 1.f : 0.f;
    float vx1 = (x1 >= 0 && x1 < 64) ? 1.f : 0.f;
    int cy0 = min(max(y0, 0), 63) << 6, cy1 = min(max(y1, 0), 63) << 6;
    int cx0 = min(max(x0, 0), 63), cx1 = min(max(x1, 0), 63);
    s_gi[kk][pix] = make_int4((cy0 + cx0) << 8, (cy0 + cx1) << 8,
                              (cy1 + cx0) << 8, (cy1 + cx1) << 8);
    s_gw[kk][pix] = make_float4((1.f - ly) * (1.f - lx) * vy0 * vx0,
                                (1.f - ly) * lx * vy0 * vx1,
                                ly * (1.f - lx) * vy1 * vx0,
                                ly * lx * vy1 * vx1);
  }
  __syncthreads();

  // ======== phase 3: main loop (R13 deform10 verbatim) ========
  float4v acc[2][4];
#pragma unroll
  for (int a = 0; a < 2; ++a)
#pragma unroll
    for (int b = 0; b < 4; ++b) acc[a][b] = (float4v)0.f;

  uint4 TA[4], TB[4];

  auto issue = [&](uint4 (&T)[4], int kk, int cg) {
    int4 g = s_gi[kk][p];
    int cb = (cg << 6) + (coct << 3);
    T[0] = *reinterpret_cast<const uint4*>(xTn + g.x + cb);
    T[1] = *reinterpret_cast<const uint4*>(xTn + g.y + cb);
    T[2] = *reinterpret_cast<const uint4*>(xTn + g.z + cb);
    T[3] = *reinterpret_cast<const uint4*>(xTn + g.w + cb);
  };

  auto step = [&](uint4 (&T)[4], int kk, int ks0, int buf) {
    short8v wf[2][2];
#pragma unroll
    for (int ks2 = 0; ks2 < 2; ++ks2)
#pragma unroll
      for (int mf = 0; mf < 2; ++mf)
        wf[ks2][mf] = *reinterpret_cast<const short8v*>(
            &wB[(((size_t)((ks0 + ks2) * 16 + (wave << 1) + mf)) * 64 + lane) * 8]);
    float4 w = s_gw[kk][p];
    uint4 r;
    r.x = bilin_pack(T[0].x, T[1].x, T[2].x, T[3].x, w.x, w.y, w.z, w.w);
    r.y = bilin_pack(T[0].y, T[1].y, T[2].y, T[3].y, w.x, w.y, w.z, w.w);
    r.z = bilin_pack(T[0].z, T[1].z, T[2].z, T[3].z, w.x, w.y, w.z, w.w);
    r.w = bilin_pack(T[0].w, T[1].w, T[2].w, T[3].w, w.x, w.y, w.z, w.w);
    *reinterpret_cast<uint4*>(&s_val[buf][p * 64 + ((coct ^ (p & 7)) << 3)]) = r;
    asm volatile("s_waitcnt lgkmcnt(0)" ::: "memory");
    __builtin_amdgcn_s_barrier();
    __builtin_amdgcn_s_setprio(1);
#pragma unroll
    for (int ks2 = 0; ks2 < 2; ++ks2) {
#pragma unroll
      for (int pf = 0; pf < 4; ++pf) {
        int row = (pf << 4) + (lane & 15);
        int g = (ks2 << 2) + (lane >> 4);
        int slot = g ^ (row & 7);
        short8v vf = *reinterpret_cast<const short8v*>(&s_val[buf][row * 64 + slot * 8]);
#pragma unroll
        for (int mf = 0; mf < 2; ++mf)
          acc[mf][pf] = __builtin_amdgcn_mfma_f32_16x16x32_bf16(
              wf[ks2][mf], vf, acc[mf][pf], 0, 0, 0);
      }
    }
    __builtin_amdgcn_s_setprio(0);
  };

  issue(TA, 0, 0);
  for (int kk = 0; kk < 9; ++kk) {
    int ks0 = kk << 3;
    issue(TB, kk, 1);
    step(TA, kk, ks0 + 0, 0);
    issue(TA, kk, 2);
    step(TB, kk, ks0 + 2, 1);
    issue(TB, kk, 3);
    step(TA, kk, ks0 + 4, 0);
    if (kk < 8) issue(TA, kk + 1, 0);
    step(TB, kk, ks0 + 6, 1);
  }

  // ---- epilogue: out NCHW + per-block BN partials ----
#pragma unroll
  for (int mf = 0; mf < 2; ++mf) {
    int ocb = (wave << 5) + (mf << 4) + ((lane >> 4) << 2);
#pragma unroll
    for (int pf = 0; pf < 4; ++pf) {
      int wo = (pf << 4) + (lane & 15);
      float* op = out + (((size_t)(n * 256 + ocb)) * 64 + ho) * 64 + wo;
      float4v a = acc[mf][pf];
      op[0] = a[0];
      op[HW] = a[1];
      op[2 * HW] = a[2];
      op[3 * HW] = a[3];
    }
  }
  float s[2][4], q[2][4];
#pragma unroll
  for (int mf = 0; mf < 2; ++mf)
#pragma unroll
    for (int j = 0; j < 4; ++j) {
      float ss = 0.f, qq = 0.f;
#pragma unroll
      for (int pf = 0; pf < 4; ++pf) {
        float v = acc[mf][pf][j];
        ss += v;
        qq += v * v;
      }
      s[mf][j] = ss;
      q[mf][j] = qq;
    }
#pragma unroll
  for (int o = 1; o < 16; o <<= 1) {
#pragma unroll
    for (int mf = 0; mf < 2; ++mf)
#pragma unroll
      for (int j = 0; j < 4; ++j) {
        s[mf][j] += __shfl_xor(s[mf][j], o);
        q[mf][j] += __shfl_xor(q[mf][j], o);
      }
  }
  if ((lane & 15) == 0) {
#pragma unroll
    for (int mf = 0; mf < 2; ++mf)
#pragma unroll
      for (int j = 0; j < 4; ++j) {
        int oc = (wave << 5) + (mf << 4) + ((lane >> 4) << 2) + j;
        part[(size_t)oc * 512 + bid] = make_float2(s[mf][j], q[mf][j]);
      }
  }
}

__global__ __launch_bounds__(256) void k_stats_fin(const float2* __restrict__ part,
                                                   float2* __restrict__ stats) {
  int oc = blockIdx.x;
  int t = threadIdx.x;
  float2 a = part[(size_t)oc * 512 + t];
  float2 b = part[(size_t)oc * 512 + 256 + t];
  float s = a.x + b.x, q = a.y + b.y;
#pragma unroll
  for (int o = 32; o; o >>= 1) {
    s += __shfl_down(s, o);
    q += __shfl_down(q, o);
  }
  __shared__ float2 wsum[4];
  if ((t & 63) == 0) wsum[t >> 6] = make_float2(s, q);
  __syncthreads();
  if (t == 0) {
    float S = wsum[0].x + wsum[1].x + wsum[2].x + wsum[3].x;
    float Q = wsum[0].y + wsum[1].y + wsum[2].y + wsum[3].y;
    float mean = S / 32768.f;
    float var = Q / 32768.f - mean * mean;
    stats[oc] = make_float2(mean, rsqrtf(var + 1e-5f));
  }
}

// BN+SiLU, XCD-aligned: blocks for image n land on XCD n.
__global__ __launch_bounds__(256) void k_bn_silu(float* __restrict__ out,
                                                 const float2* __restrict__ stats,
                                                 const float* __restrict__ gamma,
                                                 const float* __restrict__ beta) {
  int b = blockIdx.x;
  int nb = (b & 7) * 1024 + (b >> 3);   // image = b&7
  size_t i4 = (size_t)nb * 256 + threadIdx.x;
  int ch = (int)((i4 >> 10) & 255);
  float2 st = stats[ch];
  float g = gamma[ch] * st.y;
  float bb = beta[ch] - st.x * g;
  float4 v = *(float4*)(out + i4 * 4);
  float y0 = v.x * g + bb, y1 = v.y * g + bb, y2 = v.z * g + bb, y3 = v.w * g + bb;
  v.x = y0 / (1.f + expf(-y0));
  v.y = y1 / (1.f + expf(-y1));
  v.z = y2 / (1.f + expf(-y2));
  v.w = y3 / (1.f + expf(-y3));
  *(float4*)(out + i4 * 4) = v;
}

extern "C" void kernel_launch(void* const* d_in, const int* in_sizes, int n_in,
                              void* d_out, int out_size, void* d_ws, size_t ws_size,
                              hipStream_t stream) {
  const float* x      = (const float*)d_in[0];
  const float* w_off  = (const float*)d_in[1];
  const float* b_off  = (const float*)d_in[2];
  const float* w_conv = (const float*)d_in[3];
  const float* gamma  = (const float*)d_in[4];
  const float* beta   = (const float*)d_in[5];
  float* out = (float*)d_out;

  float* ws       = (float*)d_ws;
  ushort* ws_xT   = (ushort*)(ws + 589824);           // [8][4096][256] bf16
  ushort* ws_wB   = (ushort*)(ws + 4784128);          // deform weight frags
  ushort* ws_wOB  = (ushort*)(ws + 5079040);          // offset weight frags
  float2* ws_part = (float2*)(ws + 5115904);          // [256][512] partials
  float2* ws_st   = (float2*)(ws + 5378048);          // [256] stats

  k_tx_prep<<<836, 256, 0, stream>>>(x, w_conv, w_off, ws_xT, ws_wB, ws_wOB);
  k_dfull<<<512, 512, 0, stream>>>(ws_xT, ws_wB, ws_wOB, b_off, out, ws_part);
  k_stats_fin<<<256, 256, 0, stream>>>(ws_part, ws_st);
  k_bn_silu<<<8192, 256, 0, stream>>>(out, ws_st, gamma, beta);
}